// Round 4
// baseline (9349.040 us; speedup 1.0000x reference)
//
#include <hip/hip_runtime.h>
#include <hip/hip_bf16.h>
#include <math.h>

typedef __hip_bfloat16 bf16;

#define NB      8
#define SEQ     1024
#define EDIM    512
#define E2DIM   1024
#define NHEAD   8
#define HDIM    64
#define ROWS    8192   /* NB*SEQ */
#define INV_SQRT_E 0.04419417382415922f

// ---------------------------------------------------------------------------
// Input dtype autodetect (kept: it proved inputs are fp32). flag=1 -> fp32.
// ---------------------------------------------------------------------------
__global__ __launch_bounds__(256) void detect_dtype(const unsigned short* __restrict__ x,
                                                    int* __restrict__ flag) {
    int t = threadIdx.x;
    int cnt = 0;
    for (int k = t; k < 8192; k += 256) {
        unsigned short u = x[k];
        int e = (u >> 7) & 0xFF;
        if (e >= 0xC0) cnt++;
    }
#pragma unroll
    for (int o = 32; o > 0; o >>= 1) cnt += __shfl_xor(cnt, o);
    __shared__ int red[4];
    if ((t & 63) == 0) red[t >> 6] = cnt;
    __syncthreads();
    if (t == 0) flag[0] = (red[0] + red[1] + red[2] + red[3] > 100) ? 1 : 0;
}

// ---------------------------------------------------------------------------
// Trivial per-input convert (one launch per input; no clever indexing).
// ---------------------------------------------------------------------------
__global__ __launch_bounds__(256) void cvt_one(const void* __restrict__ src,
                                               float* __restrict__ dst, int n,
                                               const int* __restrict__ flag) {
    int i = blockIdx.x * 256 + threadIdx.x;
    if (i >= n) return;
    if (flag[0]) {
        dst[i] = ((const float*)src)[i];
    } else {
        unsigned int u = ((const unsigned short*)src)[i];
        union { unsigned int b; float f; } c;
        c.b = u << 16;
        dst[i] = c.f;
    }
}

// ---------------------------------------------------------------------------
// Direct spectral fold: M[j][o] = sc * sum_m w[(m-j) mod n] * fw[m][o]
// (so that spectral_fc(x) = x @ M + fb). One thread per output element.
// ---------------------------------------------------------------------------
__global__ __launch_bounds__(256) void fold_kernel(const float* __restrict__ w,
                                                   const float* __restrict__ fw,
                                                   float* __restrict__ Mout,
                                                   int n, int lg, float sc) {
    int idx = blockIdx.x * 256 + threadIdx.x;
    if (idx >= n * n) return;
    int mask = n - 1;
    int o = idx & mask;
    int j = idx >> lg;
    float acc = 0.f;
    for (int m = 0; m < n; m++)
        acc = fmaf(w[(m - j) & mask], fw[m * n + o], acc);
    Mout[idx] = acc * sc;
}

// ---------------------------------------------------------------------------
// Naive GEMM, one thread per output element:
//   C[r][c] = act( sum_k A[r][k]*B[k][c] + bias[c] ), optional aux multiply.
// mode: 0 none, 1 gelu(exact), 2 sigmoid, 3 multiply-by-aux
// A-broadcast within wave (same r), B coalesced across c. Correctness-first.
// ---------------------------------------------------------------------------
__global__ __launch_bounds__(256) void gemm_naive(
    const float* __restrict__ A, int lda,
    const float* __restrict__ B, int ldb,
    const float* __restrict__ bias,
    float* __restrict__ Cf, int ldc,
    const float* __restrict__ aux, int ldaux,
    int Mr, int Nc, int K, int mode)
{
    int idx = blockIdx.x * 256 + threadIdx.x;
    if (idx >= Mr * Nc) return;
    int r = idx / Nc, c = idx - r * Nc;
    const float* a = A + (size_t)r * lda;
    const float* b = B + c;
    float acc = 0.f;
    for (int k = 0; k < K; k++)
        acc = fmaf(a[k], b[(size_t)k * ldb], acc);
    float v = acc;
    if (bias) v += bias[c];
    if (mode == 1)      v = 0.5f * v * (1.0f + erff(v * 0.7071067811865476f));
    else if (mode == 2) v = 1.0f / (1.0f + expf(-v));
    else if (mode == 3) v *= aux[(size_t)r * ldaux + c];
    Cf[(size_t)r * ldc + c] = v;
}

// ---------------------------------------------------------------------------
// LayerNorm over 512 features. in1 optional (added). fp32 store.
// ---------------------------------------------------------------------------
__global__ __launch_bounds__(256) void ln_kernel(
    const float* __restrict__ in0, int ld0,
    const float* __restrict__ in1, int ld1,
    const float* __restrict__ g, const float* __restrict__ bta,
    float* __restrict__ outf, int ldo)
{
    int row = blockIdx.x, tid = threadIdx.x;
    const float* p0 = in0 + (size_t)row * ld0;
    float v0 = p0[tid], v1 = p0[tid + 256];
    if (in1) {
        const float* p1 = in1 + (size_t)row * ld1;
        v0 += p1[tid]; v1 += p1[tid + 256];
    }
    float s = v0 + v1, sq = v0 * v0 + v1 * v1;
#pragma unroll
    for (int o = 32; o > 0; o >>= 1) {
        s  += __shfl_xor(s, o);
        sq += __shfl_xor(sq, o);
    }
    __shared__ float red[8];
    int wid = tid >> 6;
    if ((tid & 63) == 0) { red[wid] = s; red[4 + wid] = sq; }
    __syncthreads();
    s  = red[0] + red[1] + red[2] + red[3];
    sq = red[4] + red[5] + red[6] + red[7];
    float mean = s * (1.0f / 512.0f);
    float var  = sq * (1.0f / 512.0f) - mean * mean;
    float rstd = rsqrtf(var + 1e-5f);
    outf[(size_t)row * ldo + tid]       = (v0 - mean) * rstd * g[tid] + bta[tid];
    outf[(size_t)row * ldo + tid + 256] = (v1 - mean) * rstd * g[tid + 256] + bta[tid + 256];
}

// ---------------------------------------------------------------------------
// x2 = x1 - cat[:,512:]
// ---------------------------------------------------------------------------
__global__ __launch_bounds__(256) void sub_kernel(const float* __restrict__ x1,
                                                  const float* __restrict__ cat,
                                                  float* __restrict__ x2) {
    int i = blockIdx.x * 256 + threadIdx.x;   // over ROWS*EDIM
    if (i >= ROWS * EDIM) return;
    int r = i >> 9, c = i & 511;
    x2[i] = x1[i] - cat[((size_t)r << 10) + 512 + c];
}

// ---------------------------------------------------------------------------
// Flash attention, q==k==v, head_dim 64. One block per (b, h, 64 q-rows).
// Writes new_x into cat[:, 0:512] (ld = 1024).
// ---------------------------------------------------------------------------
#define DOT4(a, b) (fmaf((a).x, (b).x, fmaf((a).y, (b).y, fmaf((a).z, (b).z, (a).w * (b).w))))

__global__ __launch_bounds__(256) void attn_kernel(const float* __restrict__ q,
                                                   float* __restrict__ cat) {
    __shared__ float Ql[64][68];
    __shared__ float Ks[64][68];
    __shared__ float Ps[64][68];   // P transposed: Ps[s][r]
    const int bid = blockIdx.x;
    const int lt = bid & 15, hh = (bid >> 4) & 7, bb = bid >> 7;
    const int l0 = lt * 64;
    const float* qb = q + (size_t)bb * SEQ * EDIM + hh * HDIM;
    const int tid = threadIdx.x;
    const int tx = tid & 15, ty = tid >> 4;
    const int r0 = ty * 4, sb = tx * 4;

    {
        const int row = tid >> 2, d0 = (tid & 3) * 16;
        const float4* src = (const float4*)(qb + (size_t)(l0 + row) * EDIM + d0);
        float4* dst = (float4*)&Ql[row][d0];
        dst[0] = src[0]; dst[1] = src[1]; dst[2] = src[2]; dst[3] = src[3];
    }

    float o[4][4];
    float m_run[4], l_run[4];
#pragma unroll
    for (int i = 0; i < 4; i++) {
        m_run[i] = -1e30f; l_run[i] = 0.f;
#pragma unroll
        for (int j = 0; j < 4; j++) o[i][j] = 0.f;
    }

    for (int s0 = 0; s0 < SEQ; s0 += 64) {
        __syncthreads();   // prev tile's PV reads done; Ql visible (iter 0)
        {
            const int row = tid >> 2, d0 = (tid & 3) * 16;
            const float4* src = (const float4*)(qb + (size_t)(s0 + row) * EDIM + d0);
            float4* dst = (float4*)&Ks[row][d0];
            dst[0] = src[0]; dst[1] = src[1]; dst[2] = src[2]; dst[3] = src[3];
        }
        __syncthreads();

        float S[4][4];
#pragma unroll
        for (int i = 0; i < 4; i++)
#pragma unroll
            for (int j = 0; j < 4; j++) S[i][j] = 0.f;

#pragma unroll
        for (int k4 = 0; k4 < 16; k4++) {
            float4 a0 = *(const float4*)&Ql[r0 + 0][k4 * 4];
            float4 a1 = *(const float4*)&Ql[r0 + 1][k4 * 4];
            float4 a2 = *(const float4*)&Ql[r0 + 2][k4 * 4];
            float4 a3 = *(const float4*)&Ql[r0 + 3][k4 * 4];
            float4 b0 = *(const float4*)&Ks[sb + 0][k4 * 4];
            float4 b1 = *(const float4*)&Ks[sb + 1][k4 * 4];
            float4 b2 = *(const float4*)&Ks[sb + 2][k4 * 4];
            float4 b3 = *(const float4*)&Ks[sb + 3][k4 * 4];
            S[0][0] += DOT4(a0, b0); S[0][1] += DOT4(a0, b1); S[0][2] += DOT4(a0, b2); S[0][3] += DOT4(a0, b3);
            S[1][0] += DOT4(a1, b0); S[1][1] += DOT4(a1, b1); S[1][2] += DOT4(a1, b2); S[1][3] += DOT4(a1, b3);
            S[2][0] += DOT4(a2, b0); S[2][1] += DOT4(a2, b1); S[2][2] += DOT4(a2, b2); S[2][3] += DOT4(a2, b3);
            S[3][0] += DOT4(a3, b0); S[3][1] += DOT4(a3, b1); S[3][2] += DOT4(a3, b2); S[3][3] += DOT4(a3, b3);
        }

#pragma unroll
        for (int i = 0; i < 4; i++) {
#pragma unroll
            for (int j = 0; j < 4; j++) S[i][j] *= INV_SQRT_E;
            float mx = fmaxf(fmaxf(S[i][0], S[i][1]), fmaxf(S[i][2], S[i][3]));
            mx = fmaxf(mx, __shfl_xor(mx, 1));
            mx = fmaxf(mx, __shfl_xor(mx, 2));
            mx = fmaxf(mx, __shfl_xor(mx, 4));
            mx = fmaxf(mx, __shfl_xor(mx, 8));
            float mn = fmaxf(m_run[i], mx);
            float al = expf(m_run[i] - mn);
            float rs = 0.f;
#pragma unroll
            for (int j = 0; j < 4; j++) { float p = expf(S[i][j] - mn); S[i][j] = p; rs += p; }
            rs += __shfl_xor(rs, 1); rs += __shfl_xor(rs, 2);
            rs += __shfl_xor(rs, 4); rs += __shfl_xor(rs, 8);
            l_run[i] = l_run[i] * al + rs;
            m_run[i] = mn;
#pragma unroll
            for (int j = 0; j < 4; j++) o[i][j] *= al;
        }
#pragma unroll
        for (int j = 0; j < 4; j++)
            *(float4*)&Ps[sb + j][r0] = make_float4(S[0][j], S[1][j], S[2][j], S[3][j]);
        __syncthreads();

#pragma unroll 4
        for (int s = 0; s < 64; s++) {
            float4 pv = *(const float4*)&Ps[s][r0];
            float4 kv = *(const float4*)&Ks[s][sb];
            o[0][0] = fmaf(pv.x, kv.x, o[0][0]); o[0][1] = fmaf(pv.x, kv.y, o[0][1]);
            o[0][2] = fmaf(pv.x, kv.z, o[0][2]); o[0][3] = fmaf(pv.x, kv.w, o[0][3]);
            o[1][0] = fmaf(pv.y, kv.x, o[1][0]); o[1][1] = fmaf(pv.y, kv.y, o[1][1]);
            o[1][2] = fmaf(pv.y, kv.z, o[1][2]); o[1][3] = fmaf(pv.y, kv.w, o[1][3]);
            o[2][0] = fmaf(pv.z, kv.x, o[2][0]); o[2][1] = fmaf(pv.z, kv.y, o[2][1]);
            o[2][2] = fmaf(pv.z, kv.z, o[2][2]); o[2][3] = fmaf(pv.z, kv.w, o[2][3]);
            o[3][0] = fmaf(pv.w, kv.x, o[3][0]); o[3][1] = fmaf(pv.w, kv.y, o[3][1]);
            o[3][2] = fmaf(pv.w, kv.z, o[3][2]); o[3][3] = fmaf(pv.w, kv.w, o[3][3]);
        }
    }

#pragma unroll
    for (int i = 0; i < 4; i++) {
        float inv = 1.0f / l_run[i];
        float* dst = cat + (size_t)(bb * SEQ + l0 + r0 + i) * E2DIM + hh * HDIM + sb;
        *(float4*)dst = make_float4(o[i][0] * inv, o[i][1] * inv, o[i][2] * inv, o[i][3] * inv);
    }
}

// ---------------------------------------------------------------------------
// Host launch
// ---------------------------------------------------------------------------
extern "C" void kernel_launch(void* const* d_in, const int* in_sizes, int n_in,
                              void* d_out, int out_size, void* d_ws, size_t ws_size,
                              hipStream_t stream)
{
    // ---- workspace layout (float offsets) ----
    const size_t OFF_M0  = 0;
    const size_t OFF_M1  = OFF_M0 + 512 * 512;
    const size_t OFF_M2  = OFF_M1 + 512 * 512;
    const size_t OFF_M3  = OFF_M2 + 512 * 512;
    const size_t OFF_M4  = OFF_M3 + 512 * 512;
    const size_t OFF_M5  = OFF_M4 + 1024 * 1024;
    const size_t OFF_CAT = OFF_M5 + 1024 * 1024;          // [8192,1024]
    const size_t OFF_A   = OFF_CAT + (size_t)8192 * 1024; // q / x2 / (s3 low half)
    const size_t OFF_C   = OFF_A + (size_t)8192 * 512;    // x1 / s1 / (s3 high half)
    const size_t OFF_D   = OFF_C + (size_t)8192 * 512;    // h
    const size_t OFF_P   = OFF_D + (size_t)8192 * 512;    // fp32-converted inputs

    float* W   = (float*)d_ws;
    float* M[6] = {W + OFF_M0, W + OFF_M1, W + OFF_M2, W + OFF_M3, W + OFF_M4, W + OFF_M5};
    float* CAT = W + OFF_CAT;
    float* BA  = W + OFF_A;
    float* BC  = W + OFF_C;
    float* BD  = W + OFF_D;

    // ---- converted-parameter pointers ----
    float* F[23];
    int pre = 0;
    for (int i = 0; i < 23 && i < n_in; i++) {
        F[i] = W + OFF_P + (size_t)pre;
        pre += in_sizes[i];
    }
    int* FLAG = (int*)(W + OFF_P + (size_t)pre);

    if (ws_size < (OFF_P + (size_t)pre + 16) * sizeof(float)) return;
    if (n_in < 23) return;

    detect_dtype<<<1, 256, 0, stream>>>((const unsigned short*)d_in[0], FLAG);
    for (int i = 0; i < 23; i++) {
        int n = in_sizes[i];
        cvt_one<<<(n + 255) / 256, 256, 0, stream>>>(d_in[i], F[i], n, FLAG);
    }

    // ---- build the 6 folded spectral matrices (direct reduction) ----
    const int wi[6] = {1, 4, 7, 10, 13, 16};
    for (int s = 0; s < 6; s++) {
        const int n  = (s < 4) ? 512 : 1024;
        const int lg = (s < 4) ? 9 : 10;
        const float sc = (s < 4) ? 0.04419417382415922f : 0.03125f;  // 1/sqrt(n)
        fold_kernel<<<(n * n + 255) / 256, 256, 0, stream>>>(F[wi[s]], F[wi[s] + 1],
                                                             M[s], n, lg, sc);
    }

    float* out0 = (float*)d_out;                       // LN(h): [8192,512] fp32
    float* out1 = (float*)d_out + (size_t)8192 * 512;  // out:   [8192,1024] fp32

    // q = x @ M0 + attn_fb                                  -> BA [8192,512]
    gemm_naive<<<(ROWS * 512 + 255) / 256, 256, 0, stream>>>(
        F[0], 512, M[0], 512, F[3], BA, 512, nullptr, 0, ROWS, 512, 512, 0);
    // attention -> new_x into cat[:, 0:512]
    attn_kernel<<<1024, 256, 0, stream>>>(BA, CAT);
    // x1 = LN(x + new_x; n1)                                -> BC
    ln_kernel<<<8192, 256, 0, stream>>>(F[0], 512, CAT, 1024, F[19], F[20], BC, 512);
    // x_ln = gelu(x1 @ M1 + ln0_fb)                          -> cat[:, 512:]
    gemm_naive<<<(ROWS * 512 + 255) / 256, 256, 0, stream>>>(
        BC, 512, M[1], 512, F[6], CAT + 512, 1024, nullptr, 0, ROWS, 512, 512, 1);
    // x2 = x1 - x_ln                                         -> BA
    sub_kernel<<<(ROWS * 512 + 255) / 256, 256, 0, stream>>>(BC, CAT, BA);
    // s1 = sigmoid(x2 @ M2 + ln1_fb)                         -> BC
    gemm_naive<<<(ROWS * 512 + 255) / 256, 256, 0, stream>>>(
        BA, 512, M[2], 512, F[9], BC, 512, nullptr, 0, ROWS, 512, 512, 2);
    // h = s1 * (x2 @ M3 + ln2_fb)                            -> BD
    gemm_naive<<<(ROWS * 512 + 255) / 256, 256, 0, stream>>>(
        BA, 512, M[3], 512, F[12], BD, 512, BC, 512, ROWS, 512, 512, 3);
    // out0 = LN(h; n2)                                       -> d_out (fp32)
    ln_kernel<<<8192, 256, 0, stream>>>(BD, 512, nullptr, 0, F[21], F[22], out0, 512);
    // s3 = sigmoid(cat @ M4 + ln3_fb)                        -> BA (spans A+C, both dead)
    gemm_naive<<<(ROWS * 1024 + 255) / 256, 256, 0, stream>>>(
        CAT, 1024, M[4], 1024, F[15], BA, 1024, nullptr, 0, ROWS, 1024, 1024, 2);
    // out1 = s3 * (cat @ M5 + ln4_fb)                        -> d_out+4M (fp32)
    gemm_naive<<<(ROWS * 1024 + 255) / 256, 256, 0, stream>>>(
        CAT, 1024, M[5], 1024, F[18], out1, 1024, BA, 1024, ROWS, 1024, 1024, 3);
}

// Round 5
// 1596.719 us; speedup vs baseline: 5.8552x; 5.8552x over previous
//
#include <hip/hip_runtime.h>
#include <hip/hip_bf16.h>
#include <math.h>

typedef __hip_bfloat16 bf16;

#define NB      8
#define SEQ     1024
#define EDIM    512
#define E2DIM   1024
#define NHEAD   8
#define HDIM    64
#define ROWS    8192   /* NB*SEQ */
#define INV_SQRT_E 0.04419417382415922f

// ---------------------------------------------------------------------------
// Input dtype autodetect (proved inputs are fp32; kept as cheap insurance).
// ---------------------------------------------------------------------------
__global__ __launch_bounds__(256) void detect_dtype(const unsigned short* __restrict__ x,
                                                    int* __restrict__ flag) {
    int t = threadIdx.x;
    int cnt = 0;
    for (int k = t; k < 8192; k += 256) {
        unsigned short u = x[k];
        int e = (u >> 7) & 0xFF;
        if (e >= 0xC0) cnt++;
    }
#pragma unroll
    for (int o = 32; o > 0; o >>= 1) cnt += __shfl_xor(cnt, o);
    __shared__ int red[4];
    if ((t & 63) == 0) red[t >> 6] = cnt;
    __syncthreads();
    if (t == 0) flag[0] = (red[0] + red[1] + red[2] + red[3] > 100) ? 1 : 0;
}

// ---------------------------------------------------------------------------
// Batch conversion of all 23 inputs -> fp32 workspace (dtype-adaptive).
// ---------------------------------------------------------------------------
struct CvtBatch {
    const void* src[23];
    float4*     dst[23];
    int         pre4[24];
};

__global__ __launch_bounds__(256) void cvt_all(CvtBatch a, int total4,
                                               const int* __restrict__ flag) {
    int t = blockIdx.x * 256 + threadIdx.x;
    if (t >= total4) return;
    int lo = 0;
    while (t >= a.pre4[lo + 1]) lo++;
    int li = t - a.pre4[lo];
    if (flag[0]) {
        a.dst[lo][li] = ((const float4*)a.src[lo])[li];
    } else {
        ushort4 u = ((const ushort4*)a.src[lo])[li];
        union { unsigned int i; float f; } c;
        float4 o;
        c.i = ((unsigned)u.x) << 16; o.x = c.f;
        c.i = ((unsigned)u.y) << 16; o.y = c.f;
        c.i = ((unsigned)u.z) << 16; o.z = c.f;
        c.i = ((unsigned)u.w) << 16; o.w = c.f;
        a.dst[lo][li] = o;
    }
}

// ---------------------------------------------------------------------------
// Materialize transposed circulant: C[m][j] = w[(j-m) mod n], so that
// (C @ fw)[m][o] = sum_j w[(j-m)]*fw[j][o]  == the verified fold.
// ---------------------------------------------------------------------------
__global__ __launch_bounds__(256) void circ_kernel(const float* __restrict__ w,
                                                   float* __restrict__ out, int lg) {
    int idx = blockIdx.x * 256 + threadIdx.x;
    int mask = (1 << lg) - 1;
    int j = idx & mask;
    int m = idx >> lg;
    out[idx] = w[(j - m) & mask];
}

// ---------------------------------------------------------------------------
// Tiled fp32 GEMM: C[M,N] = act( A[M,K] @ B[K,N] * scale + bias ), opt aux.
// BM=128 BN=64 BK=16, 256 threads, 8x4 outputs/thread.
// mode: 0 none, 1 gelu(exact), 2 sigmoid, 3 multiply-by-aux
// ---------------------------------------------------------------------------
#define BM 128
#define BN 64
#define BK 16

__global__ __launch_bounds__(256) void gemm_f32(
    const float* __restrict__ A, int lda,
    const float* __restrict__ B, int ldb,
    const float* __restrict__ bias,
    float* __restrict__ C, int ldc,
    const float* __restrict__ aux, int ldaux,
    int K, int mode, float scale)
{
    __shared__ float As[BK][BM + 4];
    __shared__ float Bs[BK][BN + 4];
    const int tid = threadIdx.x;
    const int bm = blockIdx.y * BM, bn = blockIdx.x * BN;
    const int tx = tid & 15, ty = tid >> 4;
    const int arow = tid >> 1, akq = (tid & 1) * 8;
    const int brow = tid >> 4, bcol = (tid & 15) * 4;

    float acc[8][4];
#pragma unroll
    for (int i = 0; i < 8; i++)
#pragma unroll
        for (int j = 0; j < 4; j++) acc[i][j] = 0.f;

    for (int k0 = 0; k0 < K; k0 += BK) {
        float4 a0 = *(const float4*)(A + (size_t)(bm + arow) * lda + (k0 + akq));
        float4 a1 = *(const float4*)(A + (size_t)(bm + arow) * lda + (k0 + akq + 4));
        As[akq + 0][arow] = a0.x; As[akq + 1][arow] = a0.y;
        As[akq + 2][arow] = a0.z; As[akq + 3][arow] = a0.w;
        As[akq + 4][arow] = a1.x; As[akq + 5][arow] = a1.y;
        As[akq + 6][arow] = a1.z; As[akq + 7][arow] = a1.w;
        *(float4*)&Bs[brow][bcol] =
            *(const float4*)(B + (size_t)(k0 + brow) * ldb + (bn + bcol));
        __syncthreads();
#pragma unroll
        for (int kk = 0; kk < BK; ++kk) {
            float4 af0 = *(const float4*)&As[kk][ty * 8];
            float4 af1 = *(const float4*)&As[kk][ty * 8 + 4];
            float4 bf  = *(const float4*)&Bs[kk][tx * 4];
            float a_[8] = {af0.x, af0.y, af0.z, af0.w, af1.x, af1.y, af1.z, af1.w};
            float b_[4] = {bf.x, bf.y, bf.z, bf.w};
#pragma unroll
            for (int i = 0; i < 8; i++)
#pragma unroll
                for (int j = 0; j < 4; j++)
                    acc[i][j] = fmaf(a_[i], b_[j], acc[i][j]);
        }
        __syncthreads();
    }

#pragma unroll
    for (int i = 0; i < 8; i++) {
        const int r = bm + ty * 8 + i;
#pragma unroll
        for (int j = 0; j < 4; j++) {
            const int c = bn + tx * 4 + j;
            float v = acc[i][j] * scale;
            if (bias) v += bias[c];
            if (mode == 1)      v = 0.5f * v * (1.0f + erff(v * 0.7071067811865476f));
            else if (mode == 2) v = 1.0f / (1.0f + expf(-v));
            else if (mode == 3) v *= aux[(size_t)r * ldaux + c];
            C[(size_t)r * ldc + c] = v;
        }
    }
}

// ---------------------------------------------------------------------------
// LayerNorm over 512 features. in1 optional (added). fp32 store.
// ---------------------------------------------------------------------------
__global__ __launch_bounds__(256) void ln_kernel(
    const float* __restrict__ in0, int ld0,
    const float* __restrict__ in1, int ld1,
    const float* __restrict__ g, const float* __restrict__ bta,
    float* __restrict__ outf, int ldo)
{
    int row = blockIdx.x, tid = threadIdx.x;
    const float* p0 = in0 + (size_t)row * ld0;
    float v0 = p0[tid], v1 = p0[tid + 256];
    if (in1) {
        const float* p1 = in1 + (size_t)row * ld1;
        v0 += p1[tid]; v1 += p1[tid + 256];
    }
    float s = v0 + v1, sq = v0 * v0 + v1 * v1;
#pragma unroll
    for (int o = 32; o > 0; o >>= 1) {
        s  += __shfl_xor(s, o);
        sq += __shfl_xor(sq, o);
    }
    __shared__ float red[8];
    int wid = tid >> 6;
    if ((tid & 63) == 0) { red[wid] = s; red[4 + wid] = sq; }
    __syncthreads();
    s  = red[0] + red[1] + red[2] + red[3];
    sq = red[4] + red[5] + red[6] + red[7];
    float mean = s * (1.0f / 512.0f);
    float var  = sq * (1.0f / 512.0f) - mean * mean;
    float rstd = rsqrtf(var + 1e-5f);
    outf[(size_t)row * ldo + tid]       = (v0 - mean) * rstd * g[tid] + bta[tid];
    outf[(size_t)row * ldo + tid + 256] = (v1 - mean) * rstd * g[tid + 256] + bta[tid + 256];
}

// ---------------------------------------------------------------------------
// x2 = x1 - cat[:,512:]   (vectorized)
// ---------------------------------------------------------------------------
__global__ __launch_bounds__(256) void sub_kernel(const float* __restrict__ x1,
                                                  const float* __restrict__ cat,
                                                  float* __restrict__ x2) {
    int i = blockIdx.x * 256 + threadIdx.x;  // over ROWS*EDIM/4
    int e = i << 2;
    int r = e >> 9, c = e & 511;
    float4 a = *(const float4*)(x1 + e);
    float4 b = *(const float4*)(cat + ((size_t)r << 10) + 512 + c);
    float4 o;
    o.x = a.x - b.x; o.y = a.y - b.y; o.z = a.z - b.z; o.w = a.w - b.w;
    *(float4*)(x2 + e) = o;
}

// ---------------------------------------------------------------------------
// Flash attention, q==k==v, head_dim 64. One block per (b, h, 64 q-rows).
// Writes new_x into cat[:, 0:512] (ld = 1024).
// ---------------------------------------------------------------------------
#define DOT4(a, b) (fmaf((a).x, (b).x, fmaf((a).y, (b).y, fmaf((a).z, (b).z, (a).w * (b).w))))

__global__ __launch_bounds__(256) void attn_kernel(const float* __restrict__ q,
                                                   float* __restrict__ cat) {
    __shared__ float Ql[64][68];
    __shared__ float Ks[64][68];
    __shared__ float Ps[64][68];   // P transposed: Ps[s][r]
    const int bid = blockIdx.x;
    const int lt = bid & 15, hh = (bid >> 4) & 7, bb = bid >> 7;
    const int l0 = lt * 64;
    const float* qb = q + (size_t)bb * SEQ * EDIM + hh * HDIM;
    const int tid = threadIdx.x;
    const int tx = tid & 15, ty = tid >> 4;
    const int r0 = ty * 4, sb = tx * 4;

    {
        const int row = tid >> 2, d0 = (tid & 3) * 16;
        const float4* src = (const float4*)(qb + (size_t)(l0 + row) * EDIM + d0);
        float4* dst = (float4*)&Ql[row][d0];
        dst[0] = src[0]; dst[1] = src[1]; dst[2] = src[2]; dst[3] = src[3];
    }

    float o[4][4];
    float m_run[4], l_run[4];
#pragma unroll
    for (int i = 0; i < 4; i++) {
        m_run[i] = -1e30f; l_run[i] = 0.f;
#pragma unroll
        for (int j = 0; j < 4; j++) o[i][j] = 0.f;
    }

    for (int s0 = 0; s0 < SEQ; s0 += 64) {
        __syncthreads();
        {
            const int row = tid >> 2, d0 = (tid & 3) * 16;
            const float4* src = (const float4*)(qb + (size_t)(s0 + row) * EDIM + d0);
            float4* dst = (float4*)&Ks[row][d0];
            dst[0] = src[0]; dst[1] = src[1]; dst[2] = src[2]; dst[3] = src[3];
        }
        __syncthreads();

        float S[4][4];
#pragma unroll
        for (int i = 0; i < 4; i++)
#pragma unroll
            for (int j = 0; j < 4; j++) S[i][j] = 0.f;

#pragma unroll
        for (int k4 = 0; k4 < 16; k4++) {
            float4 a0 = *(const float4*)&Ql[r0 + 0][k4 * 4];
            float4 a1 = *(const float4*)&Ql[r0 + 1][k4 * 4];
            float4 a2 = *(const float4*)&Ql[r0 + 2][k4 * 4];
            float4 a3 = *(const float4*)&Ql[r0 + 3][k4 * 4];
            float4 b0 = *(const float4*)&Ks[sb + 0][k4 * 4];
            float4 b1 = *(const float4*)&Ks[sb + 1][k4 * 4];
            float4 b2 = *(const float4*)&Ks[sb + 2][k4 * 4];
            float4 b3 = *(const float4*)&Ks[sb + 3][k4 * 4];
            S[0][0] += DOT4(a0, b0); S[0][1] += DOT4(a0, b1); S[0][2] += DOT4(a0, b2); S[0][3] += DOT4(a0, b3);
            S[1][0] += DOT4(a1, b0); S[1][1] += DOT4(a1, b1); S[1][2] += DOT4(a1, b2); S[1][3] += DOT4(a1, b3);
            S[2][0] += DOT4(a2, b0); S[2][1] += DOT4(a2, b1); S[2][2] += DOT4(a2, b2); S[2][3] += DOT4(a2, b3);
            S[3][0] += DOT4(a3, b0); S[3][1] += DOT4(a3, b1); S[3][2] += DOT4(a3, b2); S[3][3] += DOT4(a3, b3);
        }

#pragma unroll
        for (int i = 0; i < 4; i++) {
#pragma unroll
            for (int j = 0; j < 4; j++) S[i][j] *= INV_SQRT_E;
            float mx = fmaxf(fmaxf(S[i][0], S[i][1]), fmaxf(S[i][2], S[i][3]));
            mx = fmaxf(mx, __shfl_xor(mx, 1));
            mx = fmaxf(mx, __shfl_xor(mx, 2));
            mx = fmaxf(mx, __shfl_xor(mx, 4));
            mx = fmaxf(mx, __shfl_xor(mx, 8));
            float mn = fmaxf(m_run[i], mx);
            float al = expf(m_run[i] - mn);
            float rs = 0.f;
#pragma unroll
            for (int j = 0; j < 4; j++) { float p = expf(S[i][j] - mn); S[i][j] = p; rs += p; }
            rs += __shfl_xor(rs, 1); rs += __shfl_xor(rs, 2);
            rs += __shfl_xor(rs, 4); rs += __shfl_xor(rs, 8);
            l_run[i] = l_run[i] * al + rs;
            m_run[i] = mn;
#pragma unroll
            for (int j = 0; j < 4; j++) o[i][j] *= al;
        }
#pragma unroll
        for (int j = 0; j < 4; j++)
            *(float4*)&Ps[sb + j][r0] = make_float4(S[0][j], S[1][j], S[2][j], S[3][j]);
        __syncthreads();

#pragma unroll 4
        for (int s = 0; s < 64; s++) {
            float4 pv = *(const float4*)&Ps[s][r0];
            float4 kv = *(const float4*)&Ks[s][sb];
            o[0][0] = fmaf(pv.x, kv.x, o[0][0]); o[0][1] = fmaf(pv.x, kv.y, o[0][1]);
            o[0][2] = fmaf(pv.x, kv.z, o[0][2]); o[0][3] = fmaf(pv.x, kv.w, o[0][3]);
            o[1][0] = fmaf(pv.y, kv.x, o[1][0]); o[1][1] = fmaf(pv.y, kv.y, o[1][1]);
            o[1][2] = fmaf(pv.y, kv.z, o[1][2]); o[1][3] = fmaf(pv.y, kv.w, o[1][3]);
            o[2][0] = fmaf(pv.z, kv.x, o[2][0]); o[2][1] = fmaf(pv.z, kv.y, o[2][1]);
            o[2][2] = fmaf(pv.z, kv.z, o[2][2]); o[2][3] = fmaf(pv.z, kv.w, o[2][3]);
            o[3][0] = fmaf(pv.w, kv.x, o[3][0]); o[3][1] = fmaf(pv.w, kv.y, o[3][1]);
            o[3][2] = fmaf(pv.w, kv.z, o[3][2]); o[3][3] = fmaf(pv.w, kv.w, o[3][3]);
        }
    }

#pragma unroll
    for (int i = 0; i < 4; i++) {
        float inv = 1.0f / l_run[i];
        float* dst = cat + (size_t)(bb * SEQ + l0 + r0 + i) * E2DIM + hh * HDIM + sb;
        *(float4*)dst = make_float4(o[i][0] * inv, o[i][1] * inv, o[i][2] * inv, o[i][3] * inv);
    }
}

// ---------------------------------------------------------------------------
// Host launch
// ---------------------------------------------------------------------------
extern "C" void kernel_launch(void* const* d_in, const int* in_sizes, int n_in,
                              void* d_out, int out_size, void* d_ws, size_t ws_size,
                              hipStream_t stream)
{
    // ---- workspace layout (float offsets) ----
    const size_t OFF_M0  = 0;
    const size_t OFF_M1  = OFF_M0 + 512 * 512;
    const size_t OFF_M2  = OFF_M1 + 512 * 512;
    const size_t OFF_M3  = OFF_M2 + 512 * 512;
    const size_t OFF_M4  = OFF_M3 + 512 * 512;
    const size_t OFF_M5  = OFF_M4 + 1024 * 1024;
    const size_t OFF_CAT = OFF_M5 + 1024 * 1024;          // [8192,1024]
    const size_t OFF_A   = OFF_CAT + (size_t)8192 * 1024; // q / x2 / circ / s3-lo
    const size_t OFF_C   = OFF_A + (size_t)8192 * 512;    // x1 / s1 / s3-hi
    const size_t OFF_D   = OFF_C + (size_t)8192 * 512;    // h
    const size_t OFF_P   = OFF_D + (size_t)8192 * 512;    // fp32-converted inputs

    float* W   = (float*)d_ws;
    float* M[6] = {W + OFF_M0, W + OFF_M1, W + OFF_M2, W + OFF_M3, W + OFF_M4, W + OFF_M5};
    float* CAT = W + OFF_CAT;
    float* BA  = W + OFF_A;
    float* BC  = W + OFF_C;
    float* BD  = W + OFF_D;

    float* F[23];
    CvtBatch cb;
    int pre = 0;
    for (int i = 0; i < 23 && i < n_in; i++) {
        cb.pre4[i] = pre;
        F[i] = W + OFF_P + (size_t)pre * 4;
        cb.src[i] = d_in[i];
        cb.dst[i] = (float4*)F[i];
        pre += in_sizes[i] / 4;
    }
    cb.pre4[23] = pre;
    const int total4 = pre;
    int* FLAG = (int*)(W + OFF_P + (size_t)total4 * 4);

    if (n_in < 23) return;
    if (ws_size < (OFF_P + (size_t)total4 * 4 + 16) * sizeof(float)) return;

    detect_dtype<<<1, 256, 0, stream>>>((const unsigned short*)d_in[0], FLAG);
    cvt_all<<<(total4 + 255) / 256, 256, 0, stream>>>(cb, total4, FLAG);

    // ---- build the 6 folded spectral matrices: M = CwT @ fw / sqrt(n) ----
    const int wi[6] = {1, 4, 7, 10, 13, 16};
    for (int s = 0; s < 6; s++) {
        const int n  = (s < 4) ? 512 : 1024;
        const int lg = (s < 4) ? 9 : 10;
        const float sc = (s < 4) ? 0.04419417382415922f : 0.03125f;  // 1/sqrt(n)
        circ_kernel<<<(n * n) / 256, 256, 0, stream>>>(F[wi[s]], BA, lg);
        gemm_f32<<<dim3(n / BN, n / BM), 256, 0, stream>>>(
            BA, n, F[wi[s] + 1], n, nullptr, M[s], n, nullptr, 0, n, 0, sc);
    }

    float* out0 = (float*)d_out;                       // LN(h): [8192,512]
    float* out1 = (float*)d_out + (size_t)8192 * 512;  // out:   [8192,1024]

    // q = x @ M0 + attn_fb                                  -> BA
    gemm_f32<<<dim3(8, 64), 256, 0, stream>>>(
        F[0], 512, M[0], 512, F[3], BA, 512, nullptr, 0, 512, 0, 1.0f);
    // attention -> new_x into cat[:, 0:512]
    attn_kernel<<<1024, 256, 0, stream>>>(BA, CAT);
    // x1 = LN(x + new_x; n1)                                -> BC
    ln_kernel<<<8192, 256, 0, stream>>>(F[0], 512, CAT, 1024, F[19], F[20], BC, 512);
    // x_ln = gelu(x1 @ M1 + ln0_fb)                          -> cat[:, 512:]
    gemm_f32<<<dim3(8, 64), 256, 0, stream>>>(
        BC, 512, M[1], 512, F[6], CAT + 512, 1024, nullptr, 0, 512, 1, 1.0f);
    // x2 = x1 - x_ln                                         -> BA
    sub_kernel<<<4096, 256, 0, stream>>>(BC, CAT, BA);
    // s1 = sigmoid(x2 @ M2 + ln1_fb)                         -> BC
    gemm_f32<<<dim3(8, 64), 256, 0, stream>>>(
        BA, 512, M[2], 512, F[9], BC, 512, nullptr, 0, 512, 2, 1.0f);
    // h = s1 * (x2 @ M3 + ln2_fb)                            -> BD
    gemm_f32<<<dim3(8, 64), 256, 0, stream>>>(
        BA, 512, M[3], 512, F[12], BD, 512, BC, 512, 512, 3, 1.0f);
    // out0 = LN(h; n2)                                       -> d_out
    ln_kernel<<<8192, 256, 0, stream>>>(BD, 512, nullptr, 0, F[21], F[22], out0, 512);
    // s3 = sigmoid(cat @ M4 + ln3_fb)                        -> BA (spans A+C, both dead)
    gemm_f32<<<dim3(16, 64), 256, 0, stream>>>(
        CAT, 1024, M[4], 1024, F[15], BA, 1024, nullptr, 0, 1024, 2, 1.0f);
    // out1 = s3 * (cat @ M5 + ln4_fb)                        -> d_out+4M
    gemm_f32<<<dim3(16, 64), 256, 0, stream>>>(
        CAT, 1024, M[5], 1024, F[18], out1, 1024, BA, 1024, 1024, 3, 1.0f);
}

// Round 6
// 841.913 us; speedup vs baseline: 11.1045x; 1.8965x over previous
//
#include <hip/hip_runtime.h>
#include <hip/hip_bf16.h>
#include <math.h>

typedef __hip_bfloat16 bf16;
typedef unsigned short u16;
typedef __attribute__((ext_vector_type(8))) short short8;
typedef __attribute__((ext_vector_type(4))) float f32x4;

#define NB      8
#define SEQ     1024
#define EDIM    512
#define E2DIM   1024
#define ROWS    8192
#define INV_SQRT_E 0.04419417382415922f

__device__ inline u16 f2bu(float f) {           // fp32 -> bf16 bits, RNE
    union { float f; unsigned u; } c; c.f = f;
    return (u16)((c.u + 0x7FFF + ((c.u >> 16) & 1)) >> 16);
}

// ---------------------------------------------------------------------------
// Input dtype autodetect (proved inputs are fp32; kept as cheap insurance).
// ---------------------------------------------------------------------------
__global__ __launch_bounds__(256) void detect_dtype(const u16* __restrict__ x,
                                                    int* __restrict__ flag) {
    int t = threadIdx.x;
    int cnt = 0;
    for (int k = t; k < 8192; k += 256) {
        int e = (x[k] >> 7) & 0xFF;
        if (e >= 0xC0) cnt++;
    }
#pragma unroll
    for (int o = 32; o > 0; o >>= 1) cnt += __shfl_xor(cnt, o);
    __shared__ int red[4];
    if ((t & 63) == 0) red[t >> 6] = cnt;
    __syncthreads();
    if (t == 0) flag[0] = (red[0] + red[1] + red[2] + red[3] > 100) ? 1 : 0;
}

// ---------------------------------------------------------------------------
// Batch conversion of all 23 inputs -> fp32 workspace (dtype-adaptive).
// ---------------------------------------------------------------------------
struct CvtBatch {
    const void* src[23];
    float4*     dst[23];
    int         pre4[24];
};

__global__ __launch_bounds__(256) void cvt_all(CvtBatch a, int total4,
                                               const int* __restrict__ flag) {
    int t = blockIdx.x * 256 + threadIdx.x;
    if (t >= total4) return;
    int lo = 0;
    while (t >= a.pre4[lo + 1]) lo++;
    int li = t - a.pre4[lo];
    if (flag[0]) {
        a.dst[lo][li] = ((const float4*)a.src[lo])[li];
    } else {
        ushort4 u = ((const ushort4*)a.src[lo])[li];
        union { unsigned int i; float f; } c;
        float4 o;
        c.i = ((unsigned)u.x) << 16; o.x = c.f;
        c.i = ((unsigned)u.y) << 16; o.y = c.f;
        c.i = ((unsigned)u.z) << 16; o.z = c.f;
        c.i = ((unsigned)u.w) << 16; o.w = c.f;
        a.dst[lo][li] = o;
    }
}

// fp32 -> bf16 elementwise (x_bf), n/4 threads
__global__ __launch_bounds__(256) void f2b_kernel(const float* __restrict__ src,
                                                  u16* __restrict__ dst, int n4) {
    int i = blockIdx.x * 256 + threadIdx.x;
    if (i >= n4) return;
    float4 a = ((const float4*)src)[i];
    ushort4 o;
    o.x = f2bu(a.x); o.y = f2bu(a.y); o.z = f2bu(a.z); o.w = f2bu(a.w);
    ((ushort4*)dst)[i] = o;
}

// transpose+convert: dst[o][m] = bf16(src[m][o]), n x n
__global__ __launch_bounds__(256) void trconv_kernel(const float* __restrict__ src,
                                                     u16* __restrict__ dst, int n) {
    __shared__ float t[32][33];
    int bx = blockIdx.x * 32, by = blockIdx.y * 32;
    int tx = threadIdx.x & 31, ty = threadIdx.x >> 5;   // 32x8
#pragma unroll
    for (int r = 0; r < 32; r += 8)
        t[ty + r][tx] = src[(size_t)(by + ty + r) * n + bx + tx];
    __syncthreads();
#pragma unroll
    for (int r = 0; r < 32; r += 8)
        dst[(size_t)(bx + ty + r) * n + by + tx] = f2bu(t[tx][ty + r]);
}

// circulant (pre-transposed B for the fold): out[j][m] = bf16(w[(m-j) mod n])
__global__ __launch_bounds__(256) void circb_kernel(const float* __restrict__ w,
                                                    u16* __restrict__ out, int lg) {
    int idx = blockIdx.x * 256 + threadIdx.x;
    int mask = (1 << lg) - 1;
    int m = idx & mask;
    int j = idx >> lg;
    out[idx] = f2bu(w[(m - j) & mask]);
}

// ---------------------------------------------------------------------------
// bf16 MFMA GEMM: C[M,N] = act( A @ B * scale + bias ), B given pre-transposed
// (Bt[n][k]).  128x128 tile, BK=32, 4 waves, each 64x64 via 4x4 mfma 16x16x32.
// Outputs: optional fp32 Cf and/or bf16 Cb. mode: 0 none,1 gelu,2 sigmoid,3 aux-mul
// ---------------------------------------------------------------------------
#define LDT 40   /* padded LDS row (bf16 elems): 32 + 8 */

__global__ __launch_bounds__(256) void gemm_bf(
    const u16* __restrict__ A, int lda,
    const u16* __restrict__ Bt, int ldb,
    const float* __restrict__ bias,
    float* __restrict__ Cf, int ldc,
    u16* __restrict__ Cb, int ldcb,
    const float* __restrict__ aux, int ldaux,
    int K, int mode, float scale)
{
    __shared__ u16 Asl[128 * LDT];
    __shared__ u16 Bsl[128 * LDT];
    const int tid = threadIdx.x;
    const int bm = blockIdx.y * 128, bn = blockIdx.x * 128;
    const int lane = tid & 63, wave = tid >> 6;
    const int wy = wave >> 1, wx = wave & 1;
    const int qd = lane >> 4, ln16 = lane & 15;
    const int sr = tid >> 2;            // 0..63
    const int sc = (tid & 3) * 8;       // 0,8,16,24 (bf16 elems)

    f32x4 acc[4][4];
#pragma unroll
    for (int i = 0; i < 4; i++)
#pragma unroll
        for (int j = 0; j < 4; j++)
#pragma unroll
            for (int r = 0; r < 4; r++) acc[i][j][r] = 0.f;

    for (int k0 = 0; k0 < K; k0 += 32) {
        *(uint4*)&Asl[sr * LDT + sc] =
            *(const uint4*)(A + (size_t)(bm + sr) * lda + k0 + sc);
        *(uint4*)&Asl[(64 + sr) * LDT + sc] =
            *(const uint4*)(A + (size_t)(bm + 64 + sr) * lda + k0 + sc);
        *(uint4*)&Bsl[sr * LDT + sc] =
            *(const uint4*)(Bt + (size_t)(bn + sr) * ldb + k0 + sc);
        *(uint4*)&Bsl[(64 + sr) * LDT + sc] =
            *(const uint4*)(Bt + (size_t)(bn + 64 + sr) * ldb + k0 + sc);
        __syncthreads();

        short8 af[4], bf_[4];
#pragma unroll
        for (int i = 0; i < 4; i++) {
            af[i]  = *(const short8*)&Asl[(wy * 64 + i * 16 + ln16) * LDT + qd * 8];
            bf_[i] = *(const short8*)&Bsl[(wx * 64 + i * 16 + ln16) * LDT + qd * 8];
        }
#pragma unroll
        for (int i = 0; i < 4; i++)
#pragma unroll
            for (int j = 0; j < 4; j++)
                acc[i][j] = __builtin_amdgcn_mfma_f32_16x16x32_bf16(
                    af[i], bf_[j], acc[i][j], 0, 0, 0);
        __syncthreads();
    }

#pragma unroll
    for (int i = 0; i < 4; i++) {
#pragma unroll
        for (int j = 0; j < 4; j++) {
            const int col = bn + wx * 64 + j * 16 + ln16;
            const float b_ = bias ? bias[col] : 0.f;
#pragma unroll
            for (int r = 0; r < 4; r++) {
                const int row = bm + wy * 64 + i * 16 + qd * 4 + r;
                float v = acc[i][j][r] * scale + b_;
                if (mode == 1)      v = 0.5f * v * (1.0f + erff(v * 0.7071067811865476f));
                else if (mode == 2) v = 1.0f / (1.0f + expf(-v));
                else if (mode == 3) v *= aux[(size_t)row * ldaux + col];
                if (Cf) Cf[(size_t)row * ldc + col] = v;
                if (Cb) Cb[(size_t)row * ldcb + col] = f2bu(v);
            }
        }
    }
}

// ---------------------------------------------------------------------------
// LayerNorm over 512 features. in1 optional (added). fp32 + optional bf16 out.
// ---------------------------------------------------------------------------
__global__ __launch_bounds__(256) void ln_kernel(
    const float* __restrict__ in0, int ld0,
    const float* __restrict__ in1, int ld1,
    const float* __restrict__ g, const float* __restrict__ bta,
    float* __restrict__ outf, int ldo,
    u16* __restrict__ outb, int ldob)
{
    int row = blockIdx.x, tid = threadIdx.x;
    const float* p0 = in0 + (size_t)row * ld0;
    float v0 = p0[tid], v1 = p0[tid + 256];
    if (in1) {
        const float* p1 = in1 + (size_t)row * ld1;
        v0 += p1[tid]; v1 += p1[tid + 256];
    }
    float s = v0 + v1, sq = v0 * v0 + v1 * v1;
#pragma unroll
    for (int o = 32; o > 0; o >>= 1) {
        s  += __shfl_xor(s, o);
        sq += __shfl_xor(sq, o);
    }
    __shared__ float red[8];
    int wid = tid >> 6;
    if ((tid & 63) == 0) { red[wid] = s; red[4 + wid] = sq; }
    __syncthreads();
    s  = red[0] + red[1] + red[2] + red[3];
    sq = red[4] + red[5] + red[6] + red[7];
    float mean = s * (1.0f / 512.0f);
    float var  = sq * (1.0f / 512.0f) - mean * mean;
    float rstd = rsqrtf(var + 1e-5f);
    float o0 = (v0 - mean) * rstd * g[tid] + bta[tid];
    float o1 = (v1 - mean) * rstd * g[tid + 256] + bta[tid + 256];
    if (outf) {
        outf[(size_t)row * ldo + tid]       = o0;
        outf[(size_t)row * ldo + tid + 256] = o1;
    }
    if (outb) {
        outb[(size_t)row * ldob + tid]       = f2bu(o0);
        outb[(size_t)row * ldob + tid + 256] = f2bu(o1);
    }
}

// ---------------------------------------------------------------------------
// x2_bf = bf16(x1 - xln), elementwise [8192x512]
// ---------------------------------------------------------------------------
__global__ __launch_bounds__(256) void sub_kernel(const float* __restrict__ x1,
                                                  const float* __restrict__ xln,
                                                  u16* __restrict__ x2b) {
    int i = blockIdx.x * 256 + threadIdx.x;   // over ROWS*EDIM/4
    int e = i << 2;
    float4 a = *(const float4*)(x1 + e);
    float4 b = *(const float4*)(xln + e);
    ushort4 o;
    o.x = f2bu(a.x - b.x); o.y = f2bu(a.y - b.y);
    o.z = f2bu(a.z - b.z); o.w = f2bu(a.w - b.w);
    *(ushort4*)(x2b + e) = o;
}

// ---------------------------------------------------------------------------
// Flash attention, q==k==v, head_dim 64. Writes new_x fp32 [8192,512] and
// bf16 into catb[:, 0:512] (ld 1024).
// ---------------------------------------------------------------------------
#define DOT4(a, b) (fmaf((a).x, (b).x, fmaf((a).y, (b).y, fmaf((a).z, (b).z, (a).w * (b).w))))

__global__ __launch_bounds__(256) void attn_kernel(const float* __restrict__ q,
                                                   float* __restrict__ newx,
                                                   u16* __restrict__ catb) {
    __shared__ float Ql[64][68];
    __shared__ float Ks[64][68];
    __shared__ float Ps[64][68];
    const int bid = blockIdx.x;
    const int lt = bid & 15, hh = (bid >> 4) & 7, bb = bid >> 7;
    const int l0 = lt * 64;
    const float* qb = q + (size_t)bb * SEQ * EDIM + hh * 64;
    const int tid = threadIdx.x;
    const int tx = tid & 15, ty = tid >> 4;
    const int r0 = ty * 4, sb = tx * 4;

    {
        const int row = tid >> 2, d0 = (tid & 3) * 16;
        const float4* src = (const float4*)(qb + (size_t)(l0 + row) * EDIM + d0);
        float4* dst = (float4*)&Ql[row][d0];
        dst[0] = src[0]; dst[1] = src[1]; dst[2] = src[2]; dst[3] = src[3];
    }

    float o[4][4];
    float m_run[4], l_run[4];
#pragma unroll
    for (int i = 0; i < 4; i++) {
        m_run[i] = -1e30f; l_run[i] = 0.f;
#pragma unroll
        for (int j = 0; j < 4; j++) o[i][j] = 0.f;
    }

    for (int s0 = 0; s0 < SEQ; s0 += 64) {
        __syncthreads();
        {
            const int row = tid >> 2, d0 = (tid & 3) * 16;
            const float4* src = (const float4*)(qb + (size_t)(s0 + row) * EDIM + d0);
            float4* dst = (float4*)&Ks[row][d0];
            dst[0] = src[0]; dst[1] = src[1]; dst[2] = src[2]; dst[3] = src[3];
        }
        __syncthreads();

        float S[4][4];
#pragma unroll
        for (int i = 0; i < 4; i++)
#pragma unroll
            for (int j = 0; j < 4; j++) S[i][j] = 0.f;

#pragma unroll
        for (int k4 = 0; k4 < 16; k4++) {
            float4 a0 = *(const float4*)&Ql[r0 + 0][k4 * 4];
            float4 a1 = *(const float4*)&Ql[r0 + 1][k4 * 4];
            float4 a2 = *(const float4*)&Ql[r0 + 2][k4 * 4];
            float4 a3 = *(const float4*)&Ql[r0 + 3][k4 * 4];
            float4 b0 = *(const float4*)&Ks[sb + 0][k4 * 4];
            float4 b1 = *(const float4*)&Ks[sb + 1][k4 * 4];
            float4 b2 = *(const float4*)&Ks[sb + 2][k4 * 4];
            float4 b3 = *(const float4*)&Ks[sb + 3][k4 * 4];
            S[0][0] += DOT4(a0, b0); S[0][1] += DOT4(a0, b1); S[0][2] += DOT4(a0, b2); S[0][3] += DOT4(a0, b3);
            S[1][0] += DOT4(a1, b0); S[1][1] += DOT4(a1, b1); S[1][2] += DOT4(a1, b2); S[1][3] += DOT4(a1, b3);
            S[2][0] += DOT4(a2, b0); S[2][1] += DOT4(a2, b1); S[2][2] += DOT4(a2, b2); S[2][3] += DOT4(a2, b3);
            S[3][0] += DOT4(a3, b0); S[3][1] += DOT4(a3, b1); S[3][2] += DOT4(a3, b2); S[3][3] += DOT4(a3, b3);
        }

#pragma unroll
        for (int i = 0; i < 4; i++) {
#pragma unroll
            for (int j = 0; j < 4; j++) S[i][j] *= INV_SQRT_E;
            float mx = fmaxf(fmaxf(S[i][0], S[i][1]), fmaxf(S[i][2], S[i][3]));
            mx = fmaxf(mx, __shfl_xor(mx, 1));
            mx = fmaxf(mx, __shfl_xor(mx, 2));
            mx = fmaxf(mx, __shfl_xor(mx, 4));
            mx = fmaxf(mx, __shfl_xor(mx, 8));
            float mn = fmaxf(m_run[i], mx);
            float al = expf(m_run[i] - mn);
            float rs = 0.f;
#pragma unroll
            for (int j = 0; j < 4; j++) { float p = expf(S[i][j] - mn); S[i][j] = p; rs += p; }
            rs += __shfl_xor(rs, 1); rs += __shfl_xor(rs, 2);
            rs += __shfl_xor(rs, 4); rs += __shfl_xor(rs, 8);
            l_run[i] = l_run[i] * al + rs;
            m_run[i] = mn;
#pragma unroll
            for (int j = 0; j < 4; j++) o[i][j] *= al;
        }
#pragma unroll
        for (int j = 0; j < 4; j++)
            *(float4*)&Ps[sb + j][r0] = make_float4(S[0][j], S[1][j], S[2][j], S[3][j]);
        __syncthreads();

#pragma unroll 4
        for (int s = 0; s < 64; s++) {
            float4 pv = *(const float4*)&Ps[s][r0];
            float4 kv = *(const float4*)&Ks[s][sb];
            o[0][0] = fmaf(pv.x, kv.x, o[0][0]); o[0][1] = fmaf(pv.x, kv.y, o[0][1]);
            o[0][2] = fmaf(pv.x, kv.z, o[0][2]); o[0][3] = fmaf(pv.x, kv.w, o[0][3]);
            o[1][0] = fmaf(pv.y, kv.x, o[1][0]); o[1][1] = fmaf(pv.y, kv.y, o[1][1]);
            o[1][2] = fmaf(pv.y, kv.z, o[1][2]); o[1][3] = fmaf(pv.y, kv.w, o[1][3]);
            o[2][0] = fmaf(pv.z, kv.x, o[2][0]); o[2][1] = fmaf(pv.z, kv.y, o[2][1]);
            o[2][2] = fmaf(pv.z, kv.z, o[2][2]); o[2][3] = fmaf(pv.z, kv.w, o[2][3]);
            o[3][0] = fmaf(pv.w, kv.x, o[3][0]); o[3][1] = fmaf(pv.w, kv.y, o[3][1]);
            o[3][2] = fmaf(pv.w, kv.z, o[3][2]); o[3][3] = fmaf(pv.w, kv.w, o[3][3]);
        }
    }

#pragma unroll
    for (int i = 0; i < 4; i++) {
        float inv = 1.0f / l_run[i];
        const int row = bb * SEQ + l0 + r0 + i;
        float4 ov = make_float4(o[i][0] * inv, o[i][1] * inv, o[i][2] * inv, o[i][3] * inv);
        *(float4*)(newx + (size_t)row * EDIM + hh * 64 + sb) = ov;
        ushort4 ub;
        ub.x = f2bu(ov.x); ub.y = f2bu(ov.y); ub.z = f2bu(ov.z); ub.w = f2bu(ov.w);
        *(ushort4*)(catb + (size_t)row * E2DIM + hh * 64 + sb) = ub;
    }
}

// ---------------------------------------------------------------------------
// Host launch
// ---------------------------------------------------------------------------
extern "C" void kernel_launch(void* const* d_in, const int* in_sizes, int n_in,
                              void* d_out, int out_size, void* d_ws, size_t ws_size,
                              hipStream_t stream)
{
    // ---- workspace layout (float units) ----
    const size_t OFF_MT0 = 0;                       // Mt bf16: 4x512^2 + 2x1024^2
    const size_t OFF_MT1 = OFF_MT0 + 131072;
    const size_t OFF_MT2 = OFF_MT1 + 131072;
    const size_t OFF_MT3 = OFF_MT2 + 131072;
    const size_t OFF_MT4 = OFF_MT3 + 131072;
    const size_t OFF_MT5 = OFF_MT4 + 524288;
    const size_t OFF_SC1 = OFF_MT5 + 524288;        // fwT scratch (bf16 <=1024^2)
    const size_t OFF_SC2 = OFF_SC1 + 524288;        // circ scratch
    const size_t OFF_XB  = OFF_SC2 + 524288;        // x_bf / x1_bf / x2_bf (bf16 8192x512)
    const size_t OFF_CB  = OFF_XB + 2097152;        // cat bf16 [8192,1024]
    const size_t OFF_BQ  = OFF_CB + 4194304;        // q / xln / s1 (fp32 8192x512)
    const size_t OFF_BN  = OFF_BQ + 4194304;        // newx / h
    const size_t OFF_BC  = OFF_BN + 4194304;        // x1 fp32
    const size_t OFF_S3  = OFF_BC + 4194304;        // s3 fp32 [8192,1024]
    const size_t OFF_P   = OFF_S3 + 8388608;        // fp32-converted inputs

    float* W = (float*)d_ws;
    u16* MT[6] = {(u16*)(W + OFF_MT0), (u16*)(W + OFF_MT1), (u16*)(W + OFF_MT2),
                  (u16*)(W + OFF_MT3), (u16*)(W + OFF_MT4), (u16*)(W + OFF_MT5)};
    u16*   SC1 = (u16*)(W + OFF_SC1);
    u16*   SC2 = (u16*)(W + OFF_SC2);
    u16*   XB  = (u16*)(W + OFF_XB);
    u16*   CB  = (u16*)(W + OFF_CB);
    float* BQ  = W + OFF_BQ;
    float* BN  = W + OFF_BN;
    float* BC  = W + OFF_BC;
    float* S3  = W + OFF_S3;

    float* F[23];
    CvtBatch cb;
    int pre = 0;
    for (int i = 0; i < 23 && i < n_in; i++) {
        cb.pre4[i] = pre;
        F[i] = W + OFF_P + (size_t)pre * 4;
        cb.src[i] = d_in[i];
        cb.dst[i] = (float4*)F[i];
        pre += in_sizes[i] / 4;
    }
    cb.pre4[23] = pre;
    const int total4 = pre;
    int* FLAG = (int*)(W + OFF_P + (size_t)total4 * 4);

    if (n_in < 23) return;
    if (ws_size < (OFF_P + (size_t)total4 * 4 + 16) * sizeof(float)) return;

    detect_dtype<<<1, 256, 0, stream>>>((const u16*)d_in[0], FLAG);
    cvt_all<<<(total4 + 255) / 256, 256, 0, stream>>>(cb, total4, FLAG);
    // x -> bf16
    f2b_kernel<<<(ROWS * EDIM / 4 + 255) / 256, 256, 0, stream>>>(F[0], XB, ROWS * EDIM / 4);

    // ---- fold: Mt[s][o][j] = sc * sum_m fw[m][o] * w[(m-j) mod n]  (bf16 out) ----
    const int wi[6] = {1, 4, 7, 10, 13, 16};
    for (int s = 0; s < 6; s++) {
        const int n  = (s < 4) ? 512 : 1024;
        const int lg = (s < 4) ? 9 : 10;
        const float sc = (s < 4) ? 0.04419417382415922f : 0.03125f;
        trconv_kernel<<<dim3(n / 32, n / 32), 256, 0, stream>>>(F[wi[s] + 1], SC1, n);
        circb_kernel<<<(n * n) / 256, 256, 0, stream>>>(F[wi[s]], SC2, lg);
        gemm_bf<<<dim3(n / 128, n / 128), 256, 0, stream>>>(
            SC1, n, SC2, n, nullptr, nullptr, 0, MT[s], n, nullptr, 0, n, 0, sc);
    }

    float* out0 = (float*)d_out;                       // LN(h): [8192,512]
    float* out1 = (float*)d_out + (size_t)ROWS * EDIM; // out:   [8192,1024]

    // q = x @ M0 + attn_fb                                  -> BQ (fp32)
    gemm_bf<<<dim3(4, 64), 256, 0, stream>>>(
        XB, 512, MT[0], 512, F[3], BQ, 512, nullptr, 0, nullptr, 0, 512, 0, 1.0f);
    // attention -> newx fp32 (BN) + cat bf16 [:, :512]
    attn_kernel<<<1024, 256, 0, stream>>>(BQ, BN, CB);
    // x1 = LN(x + newx; n1)                                 -> BC fp32 + XB bf16
    ln_kernel<<<8192, 256, 0, stream>>>(F[0], 512, BN, 512, F[19], F[20],
                                        BC, 512, XB, 512);
    // x_ln = gelu(x1 @ M1 + ln0_fb)                          -> BQ fp32 + cat[:,512:] bf16
    gemm_bf<<<dim3(4, 64), 256, 0, stream>>>(
        XB, 512, MT[1], 512, F[6], BQ, 512, CB + 512, 1024, nullptr, 0, 512, 1, 1.0f);
    // x2_bf = bf16(x1 - x_ln)                                -> XB
    sub_kernel<<<4096, 256, 0, stream>>>(BC, BQ, XB);
    // s1 = sigmoid(x2 @ M2 + ln1_fb)                         -> BQ fp32
    gemm_bf<<<dim3(4, 64), 256, 0, stream>>>(
        XB, 512, MT[2], 512, F[9], BQ, 512, nullptr, 0, nullptr, 0, 512, 2, 1.0f);
    // h = s1 * (x2 @ M3 + ln2_fb)                            -> BN fp32
    gemm_bf<<<dim3(4, 64), 256, 0, stream>>>(
        XB, 512, MT[3], 512, F[12], BN, 512, nullptr, 0, BQ, 512, 512, 3, 1.0f);
    // out0 = LN(h; n2)                                       -> d_out
    ln_kernel<<<8192, 256, 0, stream>>>(BN, 512, nullptr, 0, F[21], F[22],
                                        out0, 512, nullptr, 0);
    // s3 = sigmoid(cat @ M4 + ln3_fb)                        -> S3 fp32
    gemm_bf<<<dim3(8, 64), 256, 0, stream>>>(
        CB, 1024, MT[4], 1024, F[15], S3, 1024, nullptr, 0, nullptr, 0, 1024, 2, 1.0f);
    // out1 = s3 * (cat @ M5 + ln4_fb)                        -> d_out+4M
    gemm_bf<<<dim3(8, 64), 256, 0, stream>>>(
        CB, 1024, MT[5], 1024, F[18], out1, 1024, nullptr, 0, S3, 1024, 1024, 3, 1.0f);
}

// Round 7
// 606.396 us; speedup vs baseline: 15.4174x; 1.3884x over previous
//
#include <hip/hip_runtime.h>
#include <hip/hip_bf16.h>
#include <math.h>

typedef __hip_bfloat16 bf16;
typedef unsigned short u16;
typedef __attribute__((ext_vector_type(8))) short short8;
typedef __attribute__((ext_vector_type(4))) float f32x4;

#define NB      8
#define SEQ     1024
#define EDIM    512
#define E2DIM   1024
#define ROWS    8192
#define INV_SQRT_E 0.04419417382415922f

__device__ inline u16 f2bu(float f) {           // fp32 -> bf16 bits, RNE
    union { float f; unsigned u; } c; c.f = f;
    return (u16)((c.u + 0x7FFF + ((c.u >> 16) & 1)) >> 16);
}

// ---------------------------------------------------------------------------
// Input dtype autodetect (proved inputs are fp32; kept as cheap insurance).
// ---------------------------------------------------------------------------
__global__ __launch_bounds__(256) void detect_dtype(const u16* __restrict__ x,
                                                    int* __restrict__ flag) {
    int t = threadIdx.x;
    int cnt = 0;
    for (int k = t; k < 8192; k += 256) {
        int e = (x[k] >> 7) & 0xFF;
        if (e >= 0xC0) cnt++;
    }
#pragma unroll
    for (int o = 32; o > 0; o >>= 1) cnt += __shfl_xor(cnt, o);
    __shared__ int red[4];
    if ((t & 63) == 0) red[t >> 6] = cnt;
    __syncthreads();
    if (t == 0) flag[0] = (red[0] + red[1] + red[2] + red[3] > 100) ? 1 : 0;
}

// ---------------------------------------------------------------------------
// Batch conversion of all 23 inputs -> fp32 workspace (dtype-adaptive).
// ---------------------------------------------------------------------------
struct CvtBatch {
    const void* src[23];
    float4*     dst[23];
    int         pre4[24];
};

__global__ __launch_bounds__(256) void cvt_all(CvtBatch a, int total4,
                                               const int* __restrict__ flag) {
    int t = blockIdx.x * 256 + threadIdx.x;
    if (t >= total4) return;
    int lo = 0;
    while (t >= a.pre4[lo + 1]) lo++;
    int li = t - a.pre4[lo];
    if (flag[0]) {
        a.dst[lo][li] = ((const float4*)a.src[lo])[li];
    } else {
        ushort4 u = ((const ushort4*)a.src[lo])[li];
        union { unsigned int i; float f; } c;
        float4 o;
        c.i = ((unsigned)u.x) << 16; o.x = c.f;
        c.i = ((unsigned)u.y) << 16; o.y = c.f;
        c.i = ((unsigned)u.z) << 16; o.z = c.f;
        c.i = ((unsigned)u.w) << 16; o.w = c.f;
        a.dst[lo][li] = o;
    }
}

// fp32 -> bf16 elementwise, n/4 threads
__global__ __launch_bounds__(256) void f2b_kernel(const float* __restrict__ src,
                                                  u16* __restrict__ dst, int n4) {
    int i = blockIdx.x * 256 + threadIdx.x;
    if (i >= n4) return;
    float4 a = ((const float4*)src)[i];
    ushort4 o;
    o.x = f2bu(a.x); o.y = f2bu(a.y); o.z = f2bu(a.z); o.w = f2bu(a.w);
    ((ushort4*)dst)[i] = o;
}

// transpose+convert: dst[o][m] = bf16(src[m][o]), n x n
__global__ __launch_bounds__(256) void trconv_kernel(const float* __restrict__ src,
                                                     u16* __restrict__ dst, int n) {
    __shared__ float t[32][33];
    int bx = blockIdx.x * 32, by = blockIdx.y * 32;
    int tx = threadIdx.x & 31, ty = threadIdx.x >> 5;   // 32x8
#pragma unroll
    for (int r = 0; r < 32; r += 8)
        t[ty + r][tx] = src[(size_t)(by + ty + r) * n + bx + tx];
    __syncthreads();
#pragma unroll
    for (int r = 0; r < 32; r += 8)
        dst[(size_t)(bx + ty + r) * n + by + tx] = f2bu(t[tx][ty + r]);
}

// circulant (pre-transposed B for the fold): out[j][m] = bf16(w[(m-j) mod n])
__global__ __launch_bounds__(256) void circb_kernel(const float* __restrict__ w,
                                                    u16* __restrict__ out, int lg) {
    int idx = blockIdx.x * 256 + threadIdx.x;
    int mask = (1 << lg) - 1;
    int m = idx & mask;
    int j = idx >> lg;
    out[idx] = f2bu(w[(m - j) & mask]);
}

// ---------------------------------------------------------------------------
// bf16 MFMA GEMM: C[M,N] = act( A @ B * scale + bias ), B given pre-transposed
// (Bt[n][k]).  128x128 tile, BK=32, 4 waves, each 64x64 via 4x4 mfma 16x16x32.
// Outputs: optional fp32 Cf and/or bf16 Cb. mode: 0 none,1 gelu,2 sigmoid,3 aux-mul
// ---------------------------------------------------------------------------
#define LDT 40   /* padded LDS row (bf16 elems): 32 + 8 */

__global__ __launch_bounds__(256) void gemm_bf(
    const u16* __restrict__ A, int lda,
    const u16* __restrict__ Bt, int ldb,
    const float* __restrict__ bias,
    float* __restrict__ Cf, int ldc,
    u16* __restrict__ Cb, int ldcb,
    const float* __restrict__ aux, int ldaux,
    int K, int mode, float scale)
{
    __shared__ u16 Asl[128 * LDT];
    __shared__ u16 Bsl[128 * LDT];
    const int tid = threadIdx.x;
    const int bm = blockIdx.y * 128, bn = blockIdx.x * 128;
    const int lane = tid & 63, wave = tid >> 6;
    const int wy = wave >> 1, wx = wave & 1;
    const int qd = lane >> 4, ln16 = lane & 15;
    const int sr = tid >> 2;            // 0..63
    const int sc = (tid & 3) * 8;       // 0,8,16,24 (bf16 elems)

    f32x4 acc[4][4];
#pragma unroll
    for (int i = 0; i < 4; i++)
#pragma unroll
        for (int j = 0; j < 4; j++)
#pragma unroll
            for (int r = 0; r < 4; r++) acc[i][j][r] = 0.f;

    for (int k0 = 0; k0 < K; k0 += 32) {
        *(uint4*)&Asl[sr * LDT + sc] =
            *(const uint4*)(A + (size_t)(bm + sr) * lda + k0 + sc);
        *(uint4*)&Asl[(64 + sr) * LDT + sc] =
            *(const uint4*)(A + (size_t)(bm + 64 + sr) * lda + k0 + sc);
        *(uint4*)&Bsl[sr * LDT + sc] =
            *(const uint4*)(Bt + (size_t)(bn + sr) * ldb + k0 + sc);
        *(uint4*)&Bsl[(64 + sr) * LDT + sc] =
            *(const uint4*)(Bt + (size_t)(bn + 64 + sr) * ldb + k0 + sc);
        __syncthreads();

        short8 af[4], bf_[4];
#pragma unroll
        for (int i = 0; i < 4; i++) {
            af[i]  = *(const short8*)&Asl[(wy * 64 + i * 16 + ln16) * LDT + qd * 8];
            bf_[i] = *(const short8*)&Bsl[(wx * 64 + i * 16 + ln16) * LDT + qd * 8];
        }
#pragma unroll
        for (int i = 0; i < 4; i++)
#pragma unroll
            for (int j = 0; j < 4; j++)
                acc[i][j] = __builtin_amdgcn_mfma_f32_16x16x32_bf16(
                    af[i], bf_[j], acc[i][j], 0, 0, 0);
        __syncthreads();
    }

#pragma unroll
    for (int i = 0; i < 4; i++) {
#pragma unroll
        for (int j = 0; j < 4; j++) {
            const int col = bn + wx * 64 + j * 16 + ln16;
            const float b_ = bias ? bias[col] : 0.f;
#pragma unroll
            for (int r = 0; r < 4; r++) {
                const int row = bm + wy * 64 + i * 16 + qd * 4 + r;
                float v = acc[i][j][r] * scale + b_;
                if (mode == 1)      v = 0.5f * v * (1.0f + erff(v * 0.7071067811865476f));
                else if (mode == 2) v = 1.0f / (1.0f + expf(-v));
                else if (mode == 3) v *= aux[(size_t)row * ldaux + col];
                if (Cf) Cf[(size_t)row * ldc + col] = v;
                if (Cb) Cb[(size_t)row * ldcb + col] = f2bu(v);
            }
        }
    }
}

// ---------------------------------------------------------------------------
// LayerNorm over 512 features. in1 optional (added). fp32 + optional bf16 out.
// ---------------------------------------------------------------------------
__global__ __launch_bounds__(256) void ln_kernel(
    const float* __restrict__ in0, int ld0,
    const float* __restrict__ in1, int ld1,
    const float* __restrict__ g, const float* __restrict__ bta,
    float* __restrict__ outf, int ldo,
    u16* __restrict__ outb, int ldob)
{
    int row = blockIdx.x, tid = threadIdx.x;
    const float* p0 = in0 + (size_t)row * ld0;
    float v0 = p0[tid], v1 = p0[tid + 256];
    if (in1) {
        const float* p1 = in1 + (size_t)row * ld1;
        v0 += p1[tid]; v1 += p1[tid + 256];
    }
    float s = v0 + v1, sq = v0 * v0 + v1 * v1;
#pragma unroll
    for (int o = 32; o > 0; o >>= 1) {
        s  += __shfl_xor(s, o);
        sq += __shfl_xor(sq, o);
    }
    __shared__ float red[8];
    int wid = tid >> 6;
    if ((tid & 63) == 0) { red[wid] = s; red[4 + wid] = sq; }
    __syncthreads();
    s  = red[0] + red[1] + red[2] + red[3];
    sq = red[4] + red[5] + red[6] + red[7];
    float mean = s * (1.0f / 512.0f);
    float var  = sq * (1.0f / 512.0f) - mean * mean;
    float rstd = rsqrtf(var + 1e-5f);
    float o0 = (v0 - mean) * rstd * g[tid] + bta[tid];
    float o1 = (v1 - mean) * rstd * g[tid + 256] + bta[tid + 256];
    if (outf) {
        outf[(size_t)row * ldo + tid]       = o0;
        outf[(size_t)row * ldo + tid + 256] = o1;
    }
    if (outb) {
        outb[(size_t)row * ldob + tid]       = f2bu(o0);
        outb[(size_t)row * ldob + tid + 256] = f2bu(o1);
    }
}

// ---------------------------------------------------------------------------
// x2_bf = bf16(x1 - xln), elementwise [8192x512]
// ---------------------------------------------------------------------------
__global__ __launch_bounds__(256) void sub_kernel(const float* __restrict__ x1,
                                                  const float* __restrict__ xln,
                                                  u16* __restrict__ x2b) {
    int i = blockIdx.x * 256 + threadIdx.x;   // over ROWS*EDIM/4
    int e = i << 2;
    float4 a = *(const float4*)(x1 + e);
    float4 b = *(const float4*)(xln + e);
    ushort4 o;
    o.x = f2bu(a.x - b.x); o.y = f2bu(a.y - b.y);
    o.z = f2bu(a.z - b.z); o.w = f2bu(a.w - b.w);
    *(ushort4*)(x2b + e) = o;
}

// ---------------------------------------------------------------------------
// MFMA flash attention, q==k==v bf16, head_dim 64.
// Block = (b, h, 64 q-rows); 4 waves x 16 q-rows. K-tiles of 64 keys.
// Layouts (empirically validated by gemm_bf): A/B-frag lane&15 = non-K idx,
// quad*8+j = K idx; C/D col=lane&15, row=quad*4+reg.
// Writes newx fp32 [8192,512] and bf16 into catb[:, 0:512] (ld 1024).
// ---------------------------------------------------------------------------
#define AP 72   /* LDS pitch in bf16 elems: 16B-aligned rows, pad 8 */

__global__ __launch_bounds__(256) void attn_mfma(const u16* __restrict__ qall,
                                                 float* __restrict__ newx,
                                                 u16* __restrict__ catb) {
    __shared__ u16 Ks[64 * AP];        // [key][d]
    __shared__ u16 KsT[64 * AP];       // [d][key]
    __shared__ u16 Pw[4][16 * AP];     // per-wave P [row][key]

    const int bid = blockIdx.x;
    const int lt = bid & 15, hh = (bid >> 4) & 7, bb = bid >> 7;
    const int q0 = lt * 64;
    const int tid = threadIdx.x;
    const int wave = tid >> 6, lane = tid & 63;
    const int quad = lane >> 4, ln16 = lane & 15;

    const u16* qh = qall + (size_t)bb * SEQ * EDIM + hh * 64;  // row stride EDIM

    // Q A-fragments for this wave's 16 rows (tile row = ln16)
    const u16* qrow = qh + (size_t)(q0 + wave * 16 + ln16) * EDIM + quad * 8;
    const short8 aq0 = *(const short8*)(qrow);
    const short8 aq1 = *(const short8*)(qrow + 32);

    f32x4 oacc[4];
    float m_run[4], l_run[4];
#pragma unroll
    for (int j = 0; j < 4; j++)
#pragma unroll
        for (int r = 0; r < 4; r++) oacc[j][r] = 0.f;
#pragma unroll
    for (int r = 0; r < 4; r++) { m_run[r] = -1e30f; l_run[r] = 0.f; }

    const int sr  = tid & 63;          // staging key-row 0..63
    const int scq = (tid >> 6) * 16;   // wave-uniform d-quarter

    for (int s0 = 0; s0 < SEQ; s0 += 64) {
        __syncthreads();               // prev iter's PV reads done
        {
            const u16* krow = qh + (size_t)(s0 + sr) * EDIM + scq;
            uint4 v0 = *(const uint4*)(krow);
            uint4 v1 = *(const uint4*)(krow + 8);
            *(uint4*)&Ks[sr * AP + scq]     = v0;
            *(uint4*)&Ks[sr * AP + scq + 8] = v1;
            const u16* h0 = (const u16*)&v0;
            const u16* h1 = (const u16*)&v1;
#pragma unroll
            for (int i = 0; i < 8; i++) KsT[(scq + i) * AP + sr]     = h0[i];
#pragma unroll
            for (int i = 0; i < 8; i++) KsT[(scq + 8 + i) * AP + sr] = h1[i];
        }
        __syncthreads();

        // S[16 rows x 64 keys] = Q Kt  (4 tiles over keys)
        f32x4 S[4];
#pragma unroll
        for (int j = 0; j < 4; j++) {
            const int krw = (j * 16 + ln16) * AP + quad * 8;
            short8 b0 = *(const short8*)&Ks[krw];
            short8 b1 = *(const short8*)&Ks[krw + 32];
            f32x4 c = {0.f, 0.f, 0.f, 0.f};
            c = __builtin_amdgcn_mfma_f32_16x16x32_bf16(aq0, b0, c, 0, 0, 0);
            c = __builtin_amdgcn_mfma_f32_16x16x32_bf16(aq1, b1, c, 0, 0, 0);
            S[j] = c;
        }

        // online softmax per row (row = quad*4+r); keys j*16+ln16
#pragma unroll
        for (int r = 0; r < 4; r++) {
            float v0_ = S[0][r] * INV_SQRT_E;
            float v1_ = S[1][r] * INV_SQRT_E;
            float v2_ = S[2][r] * INV_SQRT_E;
            float v3_ = S[3][r] * INV_SQRT_E;
            float mx = fmaxf(fmaxf(v0_, v1_), fmaxf(v2_, v3_));
            mx = fmaxf(mx, __shfl_xor(mx, 1));
            mx = fmaxf(mx, __shfl_xor(mx, 2));
            mx = fmaxf(mx, __shfl_xor(mx, 4));
            mx = fmaxf(mx, __shfl_xor(mx, 8));
            float mn = fmaxf(m_run[r], mx);
            float al = expf(m_run[r] - mn);
            m_run[r] = mn;
            float p0 = expf(v0_ - mn), p1 = expf(v1_ - mn);
            float p2 = expf(v2_ - mn), p3 = expf(v3_ - mn);
            float rs = p0 + p1 + p2 + p3;
            rs += __shfl_xor(rs, 1); rs += __shfl_xor(rs, 2);
            rs += __shfl_xor(rs, 4); rs += __shfl_xor(rs, 8);
            l_run[r] = l_run[r] * al + rs;
            oacc[0][r] *= al; oacc[1][r] *= al;
            oacc[2][r] *= al; oacc[3][r] *= al;
            const int pb = (quad * 4 + r) * AP + ln16;
            Pw[wave][pb]      = f2bu(p0);
            Pw[wave][pb + 16] = f2bu(p1);
            Pw[wave][pb + 32] = f2bu(p2);
            Pw[wave][pb + 48] = f2bu(p3);
        }

        // P A-frag (same-wave LDS round-trip; in-order per wave)
        short8 pa0 = *(const short8*)&Pw[wave][ln16 * AP + quad * 8];
        short8 pa1 = *(const short8*)&Pw[wave][ln16 * AP + 32 + quad * 8];

        // O += P V   (V = K-tile; B-frag rows from KsT[d][key])
#pragma unroll
        for (int j = 0; j < 4; j++) {
            const int drw = (j * 16 + ln16) * AP + quad * 8;
            short8 b0 = *(const short8*)&KsT[drw];
            short8 b1 = *(const short8*)&KsT[drw + 32];
            oacc[j] = __builtin_amdgcn_mfma_f32_16x16x32_bf16(pa0, b0, oacc[j], 0, 0, 0);
            oacc[j] = __builtin_amdgcn_mfma_f32_16x16x32_bf16(pa1, b1, oacc[j], 0, 0, 0);
        }
    }

#pragma unroll
    for (int r = 0; r < 4; r++) {
        const float inv = 1.0f / l_run[r];
        const int row = bb * SEQ + q0 + wave * 16 + quad * 4 + r;
#pragma unroll
        for (int j = 0; j < 4; j++) {
            const float v = oacc[j][r] * inv;
            const int col = hh * 64 + j * 16 + ln16;
            newx[(size_t)row * EDIM + col] = v;
            catb[(size_t)row * E2DIM + col] = f2bu(v);
        }
    }
}

// ---------------------------------------------------------------------------
// Host launch
// ---------------------------------------------------------------------------
extern "C" void kernel_launch(void* const* d_in, const int* in_sizes, int n_in,
                              void* d_out, int out_size, void* d_ws, size_t ws_size,
                              hipStream_t stream)
{
    // ---- workspace layout (float units) ----
    const size_t OFF_MT0 = 0;
    const size_t OFF_MT1 = OFF_MT0 + 131072;
    const size_t OFF_MT2 = OFF_MT1 + 131072;
    const size_t OFF_MT3 = OFF_MT2 + 131072;
    const size_t OFF_MT4 = OFF_MT3 + 131072;
    const size_t OFF_MT5 = OFF_MT4 + 524288;
    const size_t OFF_SC1 = OFF_MT5 + 524288;        // fwT scratch (bf16 <=1024^2)
    const size_t OFF_SC2 = OFF_SC1 + 524288;        // circ scratch
    const size_t OFF_XB  = OFF_SC2 + 524288;        // x_bf / x1_bf / x2_bf
    const size_t OFF_CB  = OFF_XB + 2097152;        // cat bf16 [8192,1024]
    const size_t OFF_BQ  = OFF_CB + 4194304;        // qB bf16 / xln / s1 (fp32)
    const size_t OFF_BN  = OFF_BQ + 4194304;        // newx / h
    const size_t OFF_BC  = OFF_BN + 4194304;        // x1 fp32
    const size_t OFF_S3  = OFF_BC + 4194304;        // s3 fp32 [8192,1024]
    const size_t OFF_P   = OFF_S3 + 8388608;        // fp32-converted inputs

    float* W = (float*)d_ws;
    u16* MT[6] = {(u16*)(W + OFF_MT0), (u16*)(W + OFF_MT1), (u16*)(W + OFF_MT2),
                  (u16*)(W + OFF_MT3), (u16*)(W + OFF_MT4), (u16*)(W + OFF_MT5)};
    u16*   SC1 = (u16*)(W + OFF_SC1);
    u16*   SC2 = (u16*)(W + OFF_SC2);
    u16*   XB  = (u16*)(W + OFF_XB);
    u16*   CB  = (u16*)(W + OFF_CB);
    float* BQ  = W + OFF_BQ;
    u16*   QB  = (u16*)BQ;      // bf16 q overlays BQ (dead until x_ln GEMM)
    float* BN  = W + OFF_BN;
    float* BC  = W + OFF_BC;
    float* S3  = W + OFF_S3;

    float* F[23];
    CvtBatch cb;
    int pre = 0;
    for (int i = 0; i < 23 && i < n_in; i++) {
        cb.pre4[i] = pre;
        F[i] = W + OFF_P + (size_t)pre * 4;
        cb.src[i] = d_in[i];
        cb.dst[i] = (float4*)F[i];
        pre += in_sizes[i] / 4;
    }
    cb.pre4[23] = pre;
    const int total4 = pre;
    int* FLAG = (int*)(W + OFF_P + (size_t)total4 * 4);

    if (n_in < 23) return;
    if (ws_size < (OFF_P + (size_t)total4 * 4 + 16) * sizeof(float)) return;

    detect_dtype<<<1, 256, 0, stream>>>((const u16*)d_in[0], FLAG);
    cvt_all<<<(total4 + 255) / 256, 256, 0, stream>>>(cb, total4, FLAG);
    f2b_kernel<<<(ROWS * EDIM / 4 + 255) / 256, 256, 0, stream>>>(F[0], XB, ROWS * EDIM / 4);

    // ---- fold: Mt[s][o][j] = sc * sum_m fw[m][o] * w[(m-j) mod n]  (bf16 out) ----
    const int wi[6] = {1, 4, 7, 10, 13, 16};
    for (int s = 0; s < 6; s++) {
        const int n  = (s < 4) ? 512 : 1024;
        const int lg = (s < 4) ? 9 : 10;
        const float sc = (s < 4) ? 0.04419417382415922f : 0.03125f;
        trconv_kernel<<<dim3(n / 32, n / 32), 256, 0, stream>>>(F[wi[s] + 1], SC1, n);
        circb_kernel<<<(n * n) / 256, 256, 0, stream>>>(F[wi[s]], SC2, lg);
        gemm_bf<<<dim3(n / 128, n / 128), 256, 0, stream>>>(
            SC1, n, SC2, n, nullptr, nullptr, 0, MT[s], n, nullptr, 0, n, 0, sc);
    }

    float* out0 = (float*)d_out;                       // LN(h): [8192,512]
    float* out1 = (float*)d_out + (size_t)ROWS * EDIM; // out:   [8192,1024]

    // q = x @ M0 + attn_fb                                  -> QB (bf16 only)
    gemm_bf<<<dim3(4, 64), 256, 0, stream>>>(
        XB, 512, MT[0], 512, F[3], nullptr, 0, QB, 512, nullptr, 0, 512, 0, 1.0f);
    // attention -> newx fp32 (BN) + cat bf16 [:, :512]
    attn_mfma<<<1024, 256, 0, stream>>>(QB, BN, CB);
    // x1 = LN(x + newx; n1)                                 -> BC fp32 + XB bf16
    ln_kernel<<<8192, 256, 0, stream>>>(F[0], 512, BN, 512, F[19], F[20],
                                        BC, 512, XB, 512);
    // x_ln = gelu(x1 @ M1 + ln0_fb)                          -> BQ fp32 + cat[:,512:] bf16
    gemm_bf<<<dim3(4, 64), 256, 0, stream>>>(
        XB, 512, MT[1], 512, F[6], BQ, 512, CB + 512, 1024, nullptr, 0, 512, 1, 1.0f);
    // x2_bf = bf16(x1 - x_ln)                                -> XB
    sub_kernel<<<4096, 256, 0, stream>>>(BC, BQ, XB);
    // s1 = sigmoid(x2 @ M2 + ln1_fb)                         -> BQ fp32
    gemm_bf<<<dim3(4, 64), 256, 0, stream>>>(
        XB, 512, MT[2], 512, F[9], BQ, 512, nullptr, 0, nullptr, 0, 512, 2, 1.0f);
    // h = s1 * (x2 @ M3 + ln2_fb)                            -> BN fp32
    gemm_bf<<<dim3(4, 64), 256, 0, stream>>>(
        XB, 512, MT[3], 512, F[12], BN, 512, nullptr, 0, BQ, 512, 512, 3, 1.0f);
    // out0 = LN(h; n2)                                       -> d_out
    ln_kernel<<<8192, 256, 0, stream>>>(BN, 512, nullptr, 0, F[21], F[22],
                                        out0, 512, nullptr, 0);
    // s3 = sigmoid(cat @ M4 + ln3_fb)                        -> S3 fp32
    gemm_bf<<<dim3(8, 64), 256, 0, stream>>>(
        CB, 1024, MT[4], 1024, F[15], S3, 1024, nullptr, 0, nullptr, 0, 1024, 2, 1.0f);
    // out1 = s3 * (cat @ M5 + ln4_fb)                        -> d_out+4M
    gemm_bf<<<dim3(8, 64), 256, 0, stream>>>(
        CB, 1024, MT[5], 1024, F[18], out1, 1024, nullptr, 0, S3, 1024, 1024, 3, 1.0f);
}

// Round 8
// 448.549 us; speedup vs baseline: 20.8429x; 1.3519x over previous
//
#include <hip/hip_runtime.h>
#include <hip/hip_bf16.h>
#include <math.h>

typedef __hip_bfloat16 bf16;
typedef unsigned short u16;
typedef __attribute__((ext_vector_type(8))) short short8;
typedef __attribute__((ext_vector_type(4))) float f32x4;

#define NB      8
#define SEQ     1024
#define EDIM    512
#define E2DIM   1024
#define ROWS    8192
#define INV_SQRT_E 0.04419417382415922f
#define ATT_SCL    0.06375985678148161f   /* INV_SQRT_E * log2(e) */

__device__ inline u16 f2bu(float f) {           // fp32 -> bf16 bits, RNE
    union { float f; unsigned u; } c; c.f = f;
    return (u16)((c.u + 0x7FFF + ((c.u >> 16) & 1)) >> 16);
}

// ---------------------------------------------------------------------------
// Input dtype autodetect (proved inputs are fp32; kept as cheap insurance).
// ---------------------------------------------------------------------------
__global__ __launch_bounds__(256) void detect_dtype(const u16* __restrict__ x,
                                                    int* __restrict__ flag) {
    int t = threadIdx.x;
    int cnt = 0;
    for (int k = t; k < 8192; k += 256) {
        int e = (x[k] >> 7) & 0xFF;
        if (e >= 0xC0) cnt++;
    }
#pragma unroll
    for (int o = 32; o > 0; o >>= 1) cnt += __shfl_xor(cnt, o);
    __shared__ int red[4];
    if ((t & 63) == 0) red[t >> 6] = cnt;
    __syncthreads();
    if (t == 0) flag[0] = (red[0] + red[1] + red[2] + red[3] > 100) ? 1 : 0;
}

// ---------------------------------------------------------------------------
// Batch conversion of all 23 inputs -> fp32 workspace (dtype-adaptive).
// ---------------------------------------------------------------------------
struct CvtBatch {
    const void* src[23];
    float4*     dst[23];
    int         pre4[24];
};

__global__ __launch_bounds__(256) void cvt_all(CvtBatch a, int total4,
                                               const int* __restrict__ flag) {
    int t = blockIdx.x * 256 + threadIdx.x;
    if (t >= total4) return;
    int lo = 0;
    while (t >= a.pre4[lo + 1]) lo++;
    int li = t - a.pre4[lo];
    if (flag[0]) {
        a.dst[lo][li] = ((const float4*)a.src[lo])[li];
    } else {
        ushort4 u = ((const ushort4*)a.src[lo])[li];
        union { unsigned int i; float f; } c;
        float4 o;
        c.i = ((unsigned)u.x) << 16; o.x = c.f;
        c.i = ((unsigned)u.y) << 16; o.y = c.f;
        c.i = ((unsigned)u.z) << 16; o.z = c.f;
        c.i = ((unsigned)u.w) << 16; o.w = c.f;
        a.dst[lo][li] = o;
    }
}

// fp32 -> bf16 elementwise, n/4 threads
__global__ __launch_bounds__(256) void f2b_kernel(const float* __restrict__ src,
                                                  u16* __restrict__ dst, int n4) {
    int i = blockIdx.x * 256 + threadIdx.x;
    if (i >= n4) return;
    float4 a = ((const float4*)src)[i];
    ushort4 o;
    o.x = f2bu(a.x); o.y = f2bu(a.y); o.z = f2bu(a.z); o.w = f2bu(a.w);
    ((ushort4*)dst)[i] = o;
}

// ---------------------------------------------------------------------------
// Fold batch: 6 spectral layers, z-indexed kernels (3 launches total).
// Mt[s][o][j] = sc * sum_m fw[m][o] * w[(m-j) mod n]
// ---------------------------------------------------------------------------
struct FoldBatch {
    const float* w[6];
    const float* fw[6];
    u16* t1[6];    // fwT bf16: t1[o][m] = bf16(fw[m][o])
    u16* t2[6];    // circ bf16: t2[j][m] = bf16(w[(m-j) mod n])
    u16* mt[6];    // output Mt bf16 [n][n]
    int  n[6], lg[6];
    float sc[6];
};

__global__ __launch_bounds__(256) void fold_trconv(FoldBatch fb) {
    const int z = blockIdx.z;
    const int n = fb.n[z];
    const int bx = blockIdx.x * 32, by = blockIdx.y * 32;
    if (bx >= n || by >= n) return;
    __shared__ float t[32][33];
    const int tx = threadIdx.x & 31, ty = threadIdx.x >> 5;   // 32x8
    const float* src = fb.fw[z];
    u16* dst = fb.t1[z];
#pragma unroll
    for (int r = 0; r < 32; r += 8)
        t[ty + r][tx] = src[(size_t)(by + ty + r) * n + bx + tx];
    __syncthreads();
#pragma unroll
    for (int r = 0; r < 32; r += 8)
        dst[(size_t)(bx + ty + r) * n + by + tx] = f2bu(t[tx][ty + r]);
}

__global__ __launch_bounds__(256) void fold_circ(FoldBatch fb) {
    const int z = blockIdx.z;
    const int n = fb.n[z], lg = fb.lg[z];
    int idx = blockIdx.x * 256 + threadIdx.x;
    if (idx >= n * n) return;
    int mask = n - 1;
    int m = idx & mask;
    int j = idx >> lg;
    fb.t2[z][idx] = f2bu(fb.w[z][(m - j) & mask]);
}

#define LDT 40   /* padded LDS row (bf16 elems): 32 + 8 */

__global__ __launch_bounds__(256) void fold_gemm(FoldBatch fb) {
    const int z = blockIdx.z;
    const int n = fb.n[z];
    const int bm = blockIdx.y * 128, bn = blockIdx.x * 128;
    if (bm >= n || bn >= n) return;
    const u16* A  = fb.t1[z];
    const u16* Bt = fb.t2[z];
    u16* Mt = fb.mt[z];
    const float scale = fb.sc[z];

    __shared__ u16 Asl[128 * LDT];
    __shared__ u16 Bsl[128 * LDT];
    const int tid = threadIdx.x;
    const int lane = tid & 63, wave = tid >> 6;
    const int wy = wave >> 1, wx = wave & 1;
    const int qd = lane >> 4, ln16 = lane & 15;
    const int sr = tid >> 2;
    const int sc = (tid & 3) * 8;

    f32x4 acc[4][4];
#pragma unroll
    for (int i = 0; i < 4; i++)
#pragma unroll
        for (int j = 0; j < 4; j++)
#pragma unroll
            for (int r = 0; r < 4; r++) acc[i][j][r] = 0.f;

    for (int k0 = 0; k0 < n; k0 += 32) {
        *(uint4*)&Asl[sr * LDT + sc] = *(const uint4*)(A + (size_t)(bm + sr) * n + k0 + sc);
        *(uint4*)&Asl[(64 + sr) * LDT + sc] = *(const uint4*)(A + (size_t)(bm + 64 + sr) * n + k0 + sc);
        *(uint4*)&Bsl[sr * LDT + sc] = *(const uint4*)(Bt + (size_t)(bn + sr) * n + k0 + sc);
        *(uint4*)&Bsl[(64 + sr) * LDT + sc] = *(const uint4*)(Bt + (size_t)(bn + 64 + sr) * n + k0 + sc);
        __syncthreads();
        short8 af[4], bf_[4];
#pragma unroll
        for (int i = 0; i < 4; i++) {
            af[i]  = *(const short8*)&Asl[(wy * 64 + i * 16 + ln16) * LDT + qd * 8];
            bf_[i] = *(const short8*)&Bsl[(wx * 64 + i * 16 + ln16) * LDT + qd * 8];
        }
#pragma unroll
        for (int i = 0; i < 4; i++)
#pragma unroll
            for (int j = 0; j < 4; j++)
                acc[i][j] = __builtin_amdgcn_mfma_f32_16x16x32_bf16(af[i], bf_[j], acc[i][j], 0, 0, 0);
        __syncthreads();
    }
#pragma unroll
    for (int i = 0; i < 4; i++)
#pragma unroll
        for (int j = 0; j < 4; j++) {
            const int col = bn + wx * 64 + j * 16 + ln16;
#pragma unroll
            for (int r = 0; r < 4; r++) {
                const int row = bm + wy * 64 + i * 16 + qd * 4 + r;
                Mt[(size_t)row * n + col] = f2bu(acc[i][j][r] * scale);
            }
        }
}

// ---------------------------------------------------------------------------
// bf16 MFMA GEMM (single B): C = act( A @ B + bias ). B pre-transposed.
// 128x128 tile, BK=32, 4 waves. mode: 0 none, 1 gelu(exact).
// Optional outputs: Cf fp32, Cb bf16(v), Cb2 bf16(aux - v).
// ---------------------------------------------------------------------------
__global__ __launch_bounds__(256) void gemm_bf(
    const u16* __restrict__ A, int lda,
    const u16* __restrict__ Bt, int ldb,
    const float* __restrict__ bias,
    float* __restrict__ Cf, int ldc,
    u16* __restrict__ Cb, int ldcb,
    u16* __restrict__ Cb2, int ldcb2,
    const float* __restrict__ aux, int ldaux,
    int K, int mode)
{
    __shared__ u16 Asl[128 * LDT];
    __shared__ u16 Bsl[128 * LDT];
    const int tid = threadIdx.x;
    const int bm = blockIdx.y * 128, bn = blockIdx.x * 128;
    const int lane = tid & 63, wave = tid >> 6;
    const int wy = wave >> 1, wx = wave & 1;
    const int qd = lane >> 4, ln16 = lane & 15;
    const int sr = tid >> 2;
    const int sc = (tid & 3) * 8;

    f32x4 acc[4][4];
#pragma unroll
    for (int i = 0; i < 4; i++)
#pragma unroll
        for (int j = 0; j < 4; j++)
#pragma unroll
            for (int r = 0; r < 4; r++) acc[i][j][r] = 0.f;

    for (int k0 = 0; k0 < K; k0 += 32) {
        *(uint4*)&Asl[sr * LDT + sc] = *(const uint4*)(A + (size_t)(bm + sr) * lda + k0 + sc);
        *(uint4*)&Asl[(64 + sr) * LDT + sc] = *(const uint4*)(A + (size_t)(bm + 64 + sr) * lda + k0 + sc);
        *(uint4*)&Bsl[sr * LDT + sc] = *(const uint4*)(Bt + (size_t)(bn + sr) * ldb + k0 + sc);
        *(uint4*)&Bsl[(64 + sr) * LDT + sc] = *(const uint4*)(Bt + (size_t)(bn + 64 + sr) * ldb + k0 + sc);
        __syncthreads();
        short8 af[4], bf_[4];
#pragma unroll
        for (int i = 0; i < 4; i++) {
            af[i]  = *(const short8*)&Asl[(wy * 64 + i * 16 + ln16) * LDT + qd * 8];
            bf_[i] = *(const short8*)&Bsl[(wx * 64 + i * 16 + ln16) * LDT + qd * 8];
        }
#pragma unroll
        for (int i = 0; i < 4; i++)
#pragma unroll
            for (int j = 0; j < 4; j++)
                acc[i][j] = __builtin_amdgcn_mfma_f32_16x16x32_bf16(af[i], bf_[j], acc[i][j], 0, 0, 0);
        __syncthreads();
    }

#pragma unroll
    for (int i = 0; i < 4; i++) {
#pragma unroll
        for (int j = 0; j < 4; j++) {
            const int col = bn + wx * 64 + j * 16 + ln16;
            const float b_ = bias ? bias[col] : 0.f;
#pragma unroll
            for (int r = 0; r < 4; r++) {
                const int row = bm + wy * 64 + i * 16 + qd * 4 + r;
                float v = acc[i][j][r] + b_;
                if (mode == 1) v = 0.5f * v * (1.0f + erff(v * 0.7071067811865476f));
                if (Cf)  Cf[(size_t)row * ldc + col] = v;
                if (Cb)  Cb[(size_t)row * ldcb + col] = f2bu(v);
                if (Cb2) Cb2[(size_t)row * ldcb2 + col] =
                             f2bu(aux[(size_t)row * ldaux + col] - v);
            }
        }
    }
}

// ---------------------------------------------------------------------------
// Dual-B fused gate GEMM: C = sigmoid(A@B1 + b1) * (A@B2 + b2), fp32 out.
// Same tile structure, A staged once, 32 MFMA/iter/wave.
// ---------------------------------------------------------------------------
__global__ __launch_bounds__(256) void gemm_bf2(
    const u16* __restrict__ A, int lda,
    const u16* __restrict__ B1t, const u16* __restrict__ B2t, int ldb,
    const float* __restrict__ bias1, const float* __restrict__ bias2,
    float* __restrict__ Cf, int ldc, int K)
{
    __shared__ u16 Asl[128 * LDT];
    __shared__ u16 B1sl[128 * LDT];
    __shared__ u16 B2sl[128 * LDT];
    const int tid = threadIdx.x;
    const int bm = blockIdx.y * 128, bn = blockIdx.x * 128;
    const int lane = tid & 63, wave = tid >> 6;
    const int wy = wave >> 1, wx = wave & 1;
    const int qd = lane >> 4, ln16 = lane & 15;
    const int sr = tid >> 2;
    const int sc = (tid & 3) * 8;

    f32x4 acc1[4][4], acc2[4][4];
#pragma unroll
    for (int i = 0; i < 4; i++)
#pragma unroll
        for (int j = 0; j < 4; j++)
#pragma unroll
            for (int r = 0; r < 4; r++) { acc1[i][j][r] = 0.f; acc2[i][j][r] = 0.f; }

    for (int k0 = 0; k0 < K; k0 += 32) {
        *(uint4*)&Asl[sr * LDT + sc]  = *(const uint4*)(A   + (size_t)(bm + sr) * lda + k0 + sc);
        *(uint4*)&Asl[(64 + sr) * LDT + sc]  = *(const uint4*)(A   + (size_t)(bm + 64 + sr) * lda + k0 + sc);
        *(uint4*)&B1sl[sr * LDT + sc] = *(const uint4*)(B1t + (size_t)(bn + sr) * ldb + k0 + sc);
        *(uint4*)&B1sl[(64 + sr) * LDT + sc] = *(const uint4*)(B1t + (size_t)(bn + 64 + sr) * ldb + k0 + sc);
        *(uint4*)&B2sl[sr * LDT + sc] = *(const uint4*)(B2t + (size_t)(bn + sr) * ldb + k0 + sc);
        *(uint4*)&B2sl[(64 + sr) * LDT + sc] = *(const uint4*)(B2t + (size_t)(bn + 64 + sr) * ldb + k0 + sc);
        __syncthreads();
        short8 af[4], b1f[4], b2f[4];
#pragma unroll
        for (int i = 0; i < 4; i++) {
            af[i]  = *(const short8*)&Asl[(wy * 64 + i * 16 + ln16) * LDT + qd * 8];
            b1f[i] = *(const short8*)&B1sl[(wx * 64 + i * 16 + ln16) * LDT + qd * 8];
            b2f[i] = *(const short8*)&B2sl[(wx * 64 + i * 16 + ln16) * LDT + qd * 8];
        }
#pragma unroll
        for (int i = 0; i < 4; i++)
#pragma unroll
            for (int j = 0; j < 4; j++) {
                acc1[i][j] = __builtin_amdgcn_mfma_f32_16x16x32_bf16(af[i], b1f[j], acc1[i][j], 0, 0, 0);
                acc2[i][j] = __builtin_amdgcn_mfma_f32_16x16x32_bf16(af[i], b2f[j], acc2[i][j], 0, 0, 0);
            }
        __syncthreads();
    }

#pragma unroll
    for (int i = 0; i < 4; i++) {
#pragma unroll
        for (int j = 0; j < 4; j++) {
            const int col = bn + wx * 64 + j * 16 + ln16;
            const float b1_ = bias1[col], b2_ = bias2[col];
#pragma unroll
            for (int r = 0; r < 4; r++) {
                const int row = bm + wy * 64 + i * 16 + qd * 4 + r;
                const float g = 1.0f / (1.0f + expf(-(acc1[i][j][r] + b1_)));
                Cf[(size_t)row * ldc + col] = g * (acc2[i][j][r] + b2_);
            }
        }
    }
}

// ---------------------------------------------------------------------------
// LayerNorm over 512 features. in1b optional bf16 add. fp32 + optional bf16 out.
// ---------------------------------------------------------------------------
__global__ __launch_bounds__(256) void ln_kernel(
    const float* __restrict__ in0, int ld0,
    const u16* __restrict__ in1b, int ld1b,
    const float* __restrict__ g, const float* __restrict__ bta,
    float* __restrict__ outf, int ldo,
    u16* __restrict__ outb, int ldob)
{
    int row = blockIdx.x, tid = threadIdx.x;
    const float* p0 = in0 + (size_t)row * ld0;
    float v0 = p0[tid], v1 = p0[tid + 256];
    if (in1b) {
        const u16* p1 = in1b + (size_t)row * ld1b;
        union { unsigned u; float f; } c0, c1;
        c0.u = ((unsigned)p1[tid]) << 16;
        c1.u = ((unsigned)p1[tid + 256]) << 16;
        v0 += c0.f; v1 += c1.f;
    }
    float s = v0 + v1, sq = v0 * v0 + v1 * v1;
#pragma unroll
    for (int o = 32; o > 0; o >>= 1) {
        s  += __shfl_xor(s, o);
        sq += __shfl_xor(sq, o);
    }
    __shared__ float red[8];
    int wid = tid >> 6;
    if ((tid & 63) == 0) { red[wid] = s; red[4 + wid] = sq; }
    __syncthreads();
    s  = red[0] + red[1] + red[2] + red[3];
    sq = red[4] + red[5] + red[6] + red[7];
    float mean = s * (1.0f / 512.0f);
    float var  = sq * (1.0f / 512.0f) - mean * mean;
    float rstd = rsqrtf(var + 1e-5f);
    float o0 = (v0 - mean) * rstd * g[tid] + bta[tid];
    float o1 = (v1 - mean) * rstd * g[tid + 256] + bta[tid + 256];
    if (outf) {
        outf[(size_t)row * ldo + tid]       = o0;
        outf[(size_t)row * ldo + tid + 256] = o1;
    }
    if (outb) {
        outb[(size_t)row * ldob + tid]       = f2bu(o0);
        outb[(size_t)row * ldob + tid + 256] = f2bu(o1);
    }
}

// ---------------------------------------------------------------------------
// MFMA flash attention, q==k==v bf16, head_dim 64. exp2-domain softmax.
// Writes bf16 new_x into catb[:, 0:512] (ld 1024).
// ---------------------------------------------------------------------------
#define AP 72   /* LDS pitch in bf16 elems */

__global__ __launch_bounds__(256) void attn_mfma(const u16* __restrict__ qall,
                                                 u16* __restrict__ catb) {
    __shared__ u16 Ks[64 * AP];        // [key][d]
    __shared__ u16 KsT[64 * AP];       // [d][key]
    __shared__ u16 Pw[4][16 * AP];     // per-wave P [row][key]

    const int bid = blockIdx.x;
    const int lt = bid & 15, hh = (bid >> 4) & 7, bb = bid >> 7;
    const int q0 = lt * 64;
    const int tid = threadIdx.x;
    const int wave = tid >> 6, lane = tid & 63;
    const int quad = lane >> 4, ln16 = lane & 15;

    const u16* qh = qall + (size_t)bb * SEQ * EDIM + hh * 64;

    const u16* qrow = qh + (size_t)(q0 + wave * 16 + ln16) * EDIM + quad * 8;
    const short8 aq0 = *(const short8*)(qrow);
    const short8 aq1 = *(const short8*)(qrow + 32);

    f32x4 oacc[4];
    float m_run[4], l_run[4];
#pragma unroll
    for (int j = 0; j < 4; j++)
#pragma unroll
        for (int r = 0; r < 4; r++) oacc[j][r] = 0.f;
#pragma unroll
    for (int r = 0; r < 4; r++) { m_run[r] = -1e30f; l_run[r] = 0.f; }

    const int sr  = tid & 63;
    const int scq = (tid >> 6) * 16;

    for (int s0 = 0; s0 < SEQ; s0 += 64) {
        __syncthreads();
        {
            const u16* krow = qh + (size_t)(s0 + sr) * EDIM + scq;
            uint4 v0 = *(const uint4*)(krow);
            uint4 v1 = *(const uint4*)(krow + 8);
            *(uint4*)&Ks[sr * AP + scq]     = v0;
            *(uint4*)&Ks[sr * AP + scq + 8] = v1;
            const u16* h0 = (const u16*)&v0;
            const u16* h1 = (const u16*)&v1;
#pragma unroll
            for (int i = 0; i < 8; i++) KsT[(scq + i) * AP + sr]     = h0[i];
#pragma unroll
            for (int i = 0; i < 8; i++) KsT[(scq + 8 + i) * AP + sr] = h1[i];
        }
        __syncthreads();

        f32x4 S[4];
#pragma unroll
        for (int j = 0; j < 4; j++) {
            const int krw = (j * 16 + ln16) * AP + quad * 8;
            short8 b0 = *(const short8*)&Ks[krw];
            short8 b1 = *(const short8*)&Ks[krw + 32];
            f32x4 c = {0.f, 0.f, 0.f, 0.f};
            c = __builtin_amdgcn_mfma_f32_16x16x32_bf16(aq0, b0, c, 0, 0, 0);
            c = __builtin_amdgcn_mfma_f32_16x16x32_bf16(aq1, b1, c, 0, 0, 0);
            S[j] = c;
        }

#pragma unroll
        for (int r = 0; r < 4; r++) {
            float v0_ = S[0][r] * ATT_SCL;       // log2-domain scores
            float v1_ = S[1][r] * ATT_SCL;
            float v2_ = S[2][r] * ATT_SCL;
            float v3_ = S[3][r] * ATT_SCL;
            float mx = fmaxf(fmaxf(v0_, v1_), fmaxf(v2_, v3_));
            mx = fmaxf(mx, __shfl_xor(mx, 1));
            mx = fmaxf(mx, __shfl_xor(mx, 2));
            mx = fmaxf(mx, __shfl_xor(mx, 4));
            mx = fmaxf(mx, __shfl_xor(mx, 8));
            float mn = fmaxf(m_run[r], mx);
            float al = exp2f(m_run[r] - mn);
            m_run[r] = mn;
            float p0 = exp2f(v0_ - mn), p1 = exp2f(v1_ - mn);
            float p2 = exp2f(v2_ - mn), p3 = exp2f(v3_ - mn);
            float rs = p0 + p1 + p2 + p3;
            rs += __shfl_xor(rs, 1); rs += __shfl_xor(rs, 2);
            rs += __shfl_xor(rs, 4); rs += __shfl_xor(rs, 8);
            l_run[r] = l_run[r] * al + rs;
            oacc[0][r] *= al; oacc[1][r] *= al;
            oacc[2][r] *= al; oacc[3][r] *= al;
            const int pb = (quad * 4 + r) * AP + ln16;
            Pw[wave][pb]      = f2bu(p0);
            Pw[wave][pb + 16] = f2bu(p1);
            Pw[wave][pb + 32] = f2bu(p2);
            Pw[wave][pb + 48] = f2bu(p3);
        }

        short8 pa0 = *(const short8*)&Pw[wave][ln16 * AP + quad * 8];
        short8 pa1 = *(const short8*)&Pw[wave][ln16 * AP + 32 + quad * 8];

#pragma unroll
        for (int j = 0; j < 4; j++) {
            const int drw = (j * 16 + ln16) * AP + quad * 8;
            short8 b0 = *(const short8*)&KsT[drw];
            short8 b1 = *(const short8*)&KsT[drw + 32];
            oacc[j] = __builtin_amdgcn_mfma_f32_16x16x32_bf16(pa0, b0, oacc[j], 0, 0, 0);
            oacc[j] = __builtin_amdgcn_mfma_f32_16x16x32_bf16(pa1, b1, oacc[j], 0, 0, 0);
        }
    }

#pragma unroll
    for (int r = 0; r < 4; r++) {
        const float inv = 1.0f / l_run[r];
        const int row = bb * SEQ + q0 + wave * 16 + quad * 4 + r;
#pragma unroll
        for (int j = 0; j < 4; j++) {
            const int col = hh * 64 + j * 16 + ln16;
            catb[(size_t)row * E2DIM + col] = f2bu(oacc[j][r] * inv);
        }
    }
}

// ---------------------------------------------------------------------------
// Host launch
// ---------------------------------------------------------------------------
extern "C" void kernel_launch(void* const* d_in, const int* in_sizes, int n_in,
                              void* d_out, int out_size, void* d_ws, size_t ws_size,
                              hipStream_t stream)
{
    // ---- workspace layout (float units) ----
    const size_t OFF_MT0 = 0;
    const size_t OFF_MT1 = OFF_MT0 + 131072;
    const size_t OFF_MT2 = OFF_MT1 + 131072;
    const size_t OFF_MT3 = OFF_MT2 + 131072;
    const size_t OFF_MT4 = OFF_MT3 + 131072;
    const size_t OFF_MT5 = OFF_MT4 + 524288;
    const size_t OFF_XB  = OFF_MT5 + 524288;        // x_bf / x1_bf (bf16 8192x512)
    const size_t OFF_CB  = OFF_XB + 2097152;        // cat bf16 [8192,1024]
    const size_t OFF_BQ  = OFF_CB + 4194304;        // q bf16 -> x2 bf16
    const size_t OFF_BN  = OFF_BQ + 4194304;        // fold t1 scratch -> h fp32
    const size_t OFF_BC  = OFF_BN + 4194304;        // fold t2 scratch -> x1 fp32
    const size_t OFF_P   = OFF_BC + 4194304;        // fp32-converted inputs

    float* W = (float*)d_ws;
    u16* MT[6] = {(u16*)(W + OFF_MT0), (u16*)(W + OFF_MT1), (u16*)(W + OFF_MT2),
                  (u16*)(W + OFF_MT3), (u16*)(W + OFF_MT4), (u16*)(W + OFF_MT5)};
    u16*   XB  = (u16*)(W + OFF_XB);
    u16*   CB  = (u16*)(W + OFF_CB);
    u16*   QB  = (u16*)(W + OFF_BQ);   // q bf16; later x2 bf16 (sequential reuse)
    float* BN  = W + OFF_BN;           // h fp32 (after fold)
    float* BC  = W + OFF_BC;           // x1 fp32 (after fold)

    float* F[23];
    CvtBatch cb;
    int pre = 0;
    for (int i = 0; i < 23 && i < n_in; i++) {
        cb.pre4[i] = pre;
        F[i] = W + OFF_P + (size_t)pre * 4;
        cb.src[i] = d_in[i];
        cb.dst[i] = (float4*)F[i];
        pre += in_sizes[i] / 4;
    }
    cb.pre4[23] = pre;
    const int total4 = pre;
    int* FLAG = (int*)(W + OFF_P + (size_t)total4 * 4);

    if (n_in < 23) return;
    if (ws_size < (OFF_P + (size_t)total4 * 4 + 16) * sizeof(float)) return;

    detect_dtype<<<1, 256, 0, stream>>>((const u16*)d_in[0], FLAG);
    cvt_all<<<(total4 + 255) / 256, 256, 0, stream>>>(cb, total4, FLAG);
    f2b_kernel<<<(ROWS * EDIM / 4 + 255) / 256, 256, 0, stream>>>(F[0], XB, ROWS * EDIM / 4);

    // ---- fold (3 batched launches): scratch overlays BN/BC (dead here) ----
    FoldBatch fb;
    {
        const int wi[6] = {1, 4, 7, 10, 13, 16};
        u16* T1 = (u16*)BN;
        u16* T2 = (u16*)BC;
        size_t off = 0;
        for (int s = 0; s < 6; s++) {
            const int n = (s < 4) ? 512 : 1024;
            fb.w[s]  = F[wi[s]];
            fb.fw[s] = F[wi[s] + 1];
            fb.t1[s] = T1 + off;
            fb.t2[s] = T2 + off;
            fb.mt[s] = MT[s];
            fb.n[s]  = n;
            fb.lg[s] = (s < 4) ? 9 : 10;
            fb.sc[s] = (s < 4) ? 0.04419417382415922f : 0.03125f;
            off += (size_t)n * n;
        }
    }
    fold_trconv<<<dim3(32, 32, 6), 256, 0, stream>>>(fb);
    fold_circ<<<dim3(4096, 1, 6), 256, 0, stream>>>(fb);
    fold_gemm<<<dim3(8, 8, 6), 256, 0, stream>>>(fb);

    float* out0 = (float*)d_out;                       // LN(h): [8192,512]
    float* out1 = (float*)d_out + (size_t)ROWS * EDIM; // out:   [8192,1024]

    // q = x @ M0 + attn_fb                                  -> QB (bf16)
    gemm_bf<<<dim3(4, 64), 256, 0, stream>>>(
        XB, 512, MT[0], 512, F[3], nullptr, 0, QB, 512, nullptr, 0, nullptr, 0, 512, 0);
    // attention -> cat bf16 [:, :512]
    attn_mfma<<<1024, 256, 0, stream>>>(QB, CB);
    // x1 = LN(x + newx; n1)                                 -> BC fp32 + XB bf16
    ln_kernel<<<8192, 256, 0, stream>>>(F[0], 512, CB, 1024, F[19], F[20],
                                        BC, 512, XB, 512);
    // x_ln = gelu(x1 @ M1 + b); cat[:,512:]=bf16(v); x2=bf16(x1-v) -> QB
    gemm_bf<<<dim3(4, 64), 256, 0, stream>>>(
        XB, 512, MT[1], 512, F[6], nullptr, 0, CB + 512, 1024, QB, 512, BC, 512, 512, 1);
    // h = sigmoid(x2@M2+b2) * (x2@M3+b3)                     -> BN fp32
    gemm_bf2<<<dim3(4, 64), 256, 0, stream>>>(
        QB, 512, MT[2], MT[3], 512, F[9], F[12], BN, 512, 512);
    // out0 = LN(h; n2)                                       -> d_out
    ln_kernel<<<8192, 256, 0, stream>>>(BN, 512, nullptr, 0, F[21], F[22],
                                        out0, 512, nullptr, 0);
    // out1 = sigmoid(cat@M4+b4) * (cat@M5+b5)                -> d_out+4M
    gemm_bf2<<<dim3(8, 64), 256, 0, stream>>>(
        CB, 1024, MT[4], MT[5], 1024, F[15], F[18], out1, 1024, 1024);
}